// Round 5
// baseline (450.137 us; speedup 1.0000x reference)
//
#include <hip/hip_runtime.h>
#include <hip/hip_bf16.h>

#define NHEAD 8
#define SCALE 0.17677669529663687f  // 32^-0.5

typedef __attribute__((ext_vector_type(8))) short bf16x8;
typedef __attribute__((ext_vector_type(4))) float f32x4;
typedef __attribute__((ext_vector_type(8))) unsigned short ushort8;

__device__ inline ushort f2b(float f) {          // f32 -> bf16 bits, RNE
    unsigned u = __float_as_uint(f);
    u += 0x7FFFu + ((u >> 16) & 1u);
    return (ushort)(u >> 16);
}
__device__ inline float b2f(ushort b) {          // bf16 bits -> f32 (exact)
    return __uint_as_float(((unsigned)b) << 16);
}

__device__ inline void load_lds16(const ushort* g, ushort* l) {
    __builtin_amdgcn_global_load_lds(
        (const __attribute__((address_space(1))) unsigned*)g,
        (__attribute__((address_space(3))) unsigned*)l, 16, 0, 0);
}

// ---------- conversions / weight prep ----------
__global__ void conv_bf16(const float* __restrict__ in, ushort* __restrict__ out, int n4) {
    int i = blockIdx.x * blockDim.x + threadIdx.x;
    if (i >= n4) return;
    float4 v = ((const float4*)in)[i];
    ushort4 o;
    o.x = f2b(v.x); o.y = f2b(v.y); o.z = f2b(v.z); o.w = f2b(v.w);
    ((ushort4*)out)[i] = o;
}

// WTq[col][k] = bf16(W_qkv[k][col]);  W_qkv is [256][768]
__global__ void transpose_wqkv(const float* __restrict__ W, ushort* __restrict__ WT) {
    int col = blockIdx.x;      // 0..767
    int k   = threadIdx.x;     // 0..255
    WT[(size_t)col * 256 + k] = f2b(W[(size_t)k * 768 + col]);
}

// WTo[col][c'] = bf16(W_out[pi(c')][col]), pi(c') = (c'&31)*8 + (c'>>5)
// (absorbs the head-transpose of the attention output into the weight)
__global__ void transpose_wout(const float* __restrict__ W, ushort* __restrict__ WT) {
    int col = blockIdx.x;      // 0..255
    int cp  = threadIdx.x;     // 0..255
    int c   = ((cp & 31) * 8) + (cp >> 5);
    WT[(size_t)col * 256 + cp] = f2b(W[(size_t)c * 256 + col]);
}

// ---------- MFMA GEMM: C = A[M x 256] * BT[Ncols x 256]^T + bias ----------
// 128x128 tile, BK=32, 4 waves, 16x16x32 bf16 MFMA, global_load_lds width-16.
// MODE 0: Cf[row*256+col] = v  (f32, GEMM2 -> out)
// MODE 1: col<256   -> qb bf16 [row*256+col]   (col = head*32+dl)
//         col>=256  -> kv bf16 head-major: per row 8 heads x {k[32], v[32]}
//                      k dim d -> (d>>5)*64 + (d&31); v dim d -> (d>>5)*64 + 32 + (d&31)
template<int MODE>
__global__ __launch_bounds__(256)
void gemm_mfma(const ushort* __restrict__ A,
               const ushort* __restrict__ BT,
               const float*  __restrict__ bias,
               float* __restrict__ Cf,
               ushort* __restrict__ qb, ushort* __restrict__ kv,
               int M) {
    __shared__ ushort As[128 * 32];
    __shared__ ushort Bs[128 * 32];
    const int tid  = threadIdx.x;
    const int wid  = tid >> 6;
    const int lane = tid & 63;
    const int l15  = lane & 15, l4 = lane >> 4;
    const int wr = wid >> 1, wc = wid & 1;
    const int blockRow = blockIdx.x * 128;
    const int blockCol = blockIdx.y * 128;

    f32x4 acc[4][4] = {};

    for (int k0 = 0; k0 < 256; k0 += 32) {
        #pragma unroll
        for (int t = 0; t < 2; ++t) {
            int c   = t * 256 + wid * 64 + lane;   // 16B-chunk index
            int row = c >> 2, ko = (c & 3) * 8;
            load_lds16(A  + (size_t)(blockRow + row) * 256 + k0 + ko,
                       As + (size_t)(t * 256 + wid * 64) * 8);
            load_lds16(BT + (size_t)(blockCol + row) * 256 + k0 + ko,
                       Bs + (size_t)(t * 256 + wid * 64) * 8);
        }
        __syncthreads();
        bf16x8 af[4], bfr[4];
        #pragma unroll
        for (int m = 0; m < 4; ++m)
            af[m] = *(const bf16x8*)&As[(wr * 64 + m * 16 + l15) * 32 + l4 * 8];
        #pragma unroll
        for (int n = 0; n < 4; ++n)
            bfr[n] = *(const bf16x8*)&Bs[(wc * 64 + n * 16 + l15) * 32 + l4 * 8];
        #pragma unroll
        for (int m = 0; m < 4; ++m)
            #pragma unroll
            for (int n = 0; n < 4; ++n)
                acc[m][n] = __builtin_amdgcn_mfma_f32_16x16x32_bf16(af[m], bfr[n], acc[m][n], 0, 0, 0);
        __syncthreads();
    }

    #pragma unroll
    for (int m = 0; m < 4; ++m) {
        #pragma unroll
        for (int r = 0; r < 4; ++r) {
            int row = blockRow + wr * 64 + m * 16 + l4 * 4 + r;
            if (row >= M) continue;
            #pragma unroll
            for (int n = 0; n < 4; ++n) {
                int col = blockCol + wc * 64 + n * 16 + l15;
                float v = acc[m][n][r] + bias[col];
                if (MODE == 0) {
                    Cf[(size_t)row * 256 + col] = v;
                } else {
                    ushort b = f2b(v);
                    if (col < 256) {
                        qb[(size_t)row * 256 + col] = b;
                    } else if (col < 512) {
                        int d = col - 256;
                        kv[(size_t)row * 512 + (d >> 5) * 64 + (d & 31)] = b;
                    } else {
                        int d = col - 512;
                        kv[(size_t)row * 512 + (d >> 5) * 64 + 32 + (d & 31)] = b;
                    }
                }
            }
        }
    }
}

// ---------- CSR build ----------
__global__ void count_dst(const int* __restrict__ dst, int* __restrict__ counts, int E) {
    int i = blockIdx.x * blockDim.x + threadIdx.x;
    if (i < E) atomicAdd(&counts[dst[i]], 1);
}

// Single-workgroup exclusive scan, 1024 threads x 4 elements (int4).
__global__ void scan_offsets(const int* __restrict__ counts, int* __restrict__ offsets,
                             int* __restrict__ cursor, int N) {
    __shared__ int wsum[16];
    __shared__ int carry;
    int tid = threadIdx.x;
    int lane = tid & 63;
    int wid = tid >> 6;
    if (tid == 0) carry = 0;
    __syncthreads();
    for (int base = 0; base < N; base += 4096) {
        int i = base + tid * 4;
        int4 c = make_int4(0, 0, 0, 0);
        if (i < N) c = *(const int4*)(counts + i);
        int s = c.x + c.y + c.z + c.w;
        int x = s;
        #pragma unroll
        for (int d = 1; d < 64; d <<= 1) {
            int y = __shfl_up(x, d);
            if (lane >= d) x += y;
        }
        if (lane == 63) wsum[wid] = x;
        __syncthreads();
        if (wid == 0 && lane < 16) {
            int w = wsum[lane];
            #pragma unroll
            for (int d = 1; d < 16; d <<= 1) {
                int y = __shfl_up(w, d);
                if (lane >= d) w += y;
            }
            wsum[lane] = w;
        }
        __syncthreads();
        int pre = carry + (wid ? wsum[wid - 1] : 0) + (x - s);
        if (i < N) {
            int4 o;
            o.x = pre;
            o.y = pre + c.x;
            o.z = o.y + c.y;
            o.w = o.z + c.z;
            *(int4*)(offsets + i) = o;
            *(int4*)(cursor + i) = o;
        }
        int total = wsum[15];
        __syncthreads();
        if (tid == 0) carry += total;
        __syncthreads();
    }
    if (tid == 0) offsets[N] = carry;
}

__global__ void scatter_edges(const int* __restrict__ src, const int* __restrict__ dst,
                              int* __restrict__ cursor, ushort* __restrict__ csr_src, int E) {
    int i = blockIdx.x * blockDim.x + threadIdx.x;
    if (i < E) {
        int d = dst[i];
        int pos = atomicAdd(&cursor[d], 1);
        csr_src[pos] = (ushort)src[i];
    }
}

// ---------- per-node attention: one wave per dst node ----------
// Lane geometry: h = lane>>3 (head), half = (lane>>2)&1, j = lane&3 (edge slot).
// Each lane owns 16 dims (half of a head); 16 lanes cover one edge; 4 edges per
// iteration. Dot needs ONE shfl (xor 4); j-reduction deferred to once per node.
__global__ void node_attn(const ushort* __restrict__ qb,
                          const ushort* __restrict__ kv,
                          const int* __restrict__ offsets,
                          const ushort* __restrict__ csr_src,
                          ushort* hbuf,
                          int N) {
    int wid = threadIdx.x >> 6, lane = threadIdx.x & 63;
    int n = blockIdx.x * 4 + wid;
    if (n >= N) return;
    int j = lane & 3, half = (lane >> 2) & 1, h = lane >> 3;
    int beg = offsets[n], end = offsets[n + 1];

    const ushort* qp = qb + (size_t)n * 256 + h * 32 + half * 16;
    ushort8 q0 = *(const ushort8*)qp;
    ushort8 q1 = *(const ushort8*)(qp + 8);
    float qf[16];
    #pragma unroll
    for (int t = 0; t < 8; ++t) { qf[t] = b2f(q0[t]); qf[8 + t] = b2f(q1[t]); }

    float acc[16] = {};
    float den = 0.f;

    #pragma unroll 2
    for (int e0 = beg; e0 < end; e0 += 4) {
        int e = e0 + j;
        bool valid = e < end;
        int s = csr_src[valid ? e : beg];
        const ushort* base = kv + (size_t)s * 512 + h * 64 + half * 16;
        ushort8 k0 = *(const ushort8*)base;
        ushort8 k1 = *(const ushort8*)(base + 8);
        ushort8 v0 = *(const ushort8*)(base + 32);
        ushort8 v1 = *(const ushort8*)(base + 40);
        float p0 = 0.f, p1 = 0.f, p2 = 0.f, p3 = 0.f;
        #pragma unroll
        for (int t = 0; t < 4; ++t) {
            p0 += qf[t]      * b2f(k0[t]);
            p1 += qf[4 + t]  * b2f(k0[4 + t]);
            p2 += qf[8 + t]  * b2f(k1[t]);
            p3 += qf[12 + t] * b2f(k1[4 + t]);
        }
        float p = (p0 + p1) + (p2 + p3);
        p += __shfl_xor(p, 4);                 // other half of the 32-dot
        float sc = valid ? __expf(p * SCALE) : 0.f;
        den += sc;
        #pragma unroll
        for (int t = 0; t < 8; ++t) {
            acc[t]     += sc * b2f(v0[t]);
            acc[8 + t] += sc * b2f(v1[t]);
        }
    }

    // reduce across the 4 edge slots (lane bits 0,1)
    #pragma unroll
    for (int t = 0; t < 16; ++t) acc[t] += __shfl_xor(acc[t], 1);
    den += __shfl_xor(den, 1);
    #pragma unroll
    for (int t = 0; t < 16; ++t) acc[t] += __shfl_xor(acc[t], 2);
    den += __shfl_xor(den, 2);

    float inv = (end > beg) ? (1.0f / den) : 0.f;
    const ushort* hr = hbuf + (size_t)n * 256;
    int dbase = half * 16 + j * 4;             // dim within head this lane writes
    ushort4 o;
    #pragma unroll
    for (int t = 0; t < 4; ++t) {
        // static-index select of acc[j*4+t] (runtime j would spill to scratch)
        float a01 = (j & 1) ? acc[4 + t] : acc[t];
        float a23 = (j & 1) ? acc[12 + t] : acc[8 + t];
        float a   = (j & 2) ? a23 : a01;
        float r   = b2f(hr[(dbase + t) * 8 + h]);
        float v   = a * inv + r;
        if (t == 0) o.x = f2b(v);
        else if (t == 1) o.y = f2b(v);
        else if (t == 2) o.z = f2b(v);
        else o.w = f2b(v);
    }
    *(ushort4*)(hbuf + (size_t)n * 256 + lane * 4) = o;
}

extern "C" void kernel_launch(void* const* d_in, const int* in_sizes, int n_in,
                              void* d_out, int out_size, void* d_ws, size_t ws_size,
                              hipStream_t stream) {
    const float* h     = (const float*)d_in[0];
    const int*   src   = (const int*)d_in[1];
    const int*   dst   = (const int*)d_in[2];
    const float* W_qkv = (const float*)d_in[3];
    const float* b_qkv = (const float*)d_in[4];
    const float* W_out = (const float*)d_in[5];
    const float* b_out = (const float*)d_in[6];
    float* out = (float*)d_out;

    int N = in_sizes[0] / 256;
    int E = in_sizes[1];
    int Mpad = (N + 127) & ~127;
    int No   = (N + 16) & ~15;          // padded int stride, keeps int4 alignment

    ushort* qb   = (ushort*)d_ws;                      // Mpad*256 bf16
    ushort* kv   = qb + (size_t)Mpad * 256;            // Mpad*512 bf16 (head-major)
    ushort* Abf  = kv + (size_t)Mpad * 512;            // Mpad*256 bf16 (h, then h2)
    ushort* WTq  = Abf + (size_t)Mpad * 256;           // 768*256
    ushort* WTo  = WTq + 768 * 256;                    // 256*256
    int* counts  = (int*)(WTo + 256 * 256);            // No
    int* offsets = counts + No;                        // No+1 (uses N+1)
    int* cursor  = offsets + No;                       // No
    ushort* csr_src = (ushort*)(cursor + No);          // E (ushort: N < 65536)

    hipMemsetAsync(counts, 0, (size_t)No * sizeof(int), stream);

    conv_bf16<<<(N * 64 + 255) / 256, 256, 0, stream>>>(h, Abf, N * 64);
    transpose_wqkv<<<768, 256, 0, stream>>>(W_qkv, WTq);
    transpose_wout<<<256, 256, 0, stream>>>(W_out, WTo);

    count_dst<<<(E + 255) / 256, 256, 0, stream>>>(dst, counts, E);
    scan_offsets<<<1, 1024, 0, stream>>>(counts, offsets, cursor, N);
    scatter_edges<<<(E + 255) / 256, 256, 0, stream>>>(src, dst, cursor, csr_src, E);

    dim3 g1(Mpad / 128, 6);
    gemm_mfma<1><<<g1, 256, 0, stream>>>(Abf, WTq, b_qkv, nullptr, qb, kv, N);

    node_attn<<<(N + 3) / 4, 256, 0, stream>>>(qb, kv, offsets, csr_src, Abf, N);

    dim3 g2(Mpad / 128, 2);
    gemm_mfma<0><<<g2, 256, 0, stream>>>(Abf, WTo, b_out, out, nullptr, nullptr, N);
}

// Round 6
// 339.761 us; speedup vs baseline: 1.3249x; 1.3249x over previous
//
#include <hip/hip_runtime.h>
#include <hip/hip_bf16.h>

#define NHEAD 8
#define SCALE 0.17677669529663687f  // 32^-0.5

typedef __attribute__((ext_vector_type(8))) short bf16x8;
typedef __attribute__((ext_vector_type(4))) float f32x4;
typedef __attribute__((ext_vector_type(8))) unsigned short ushort8;

__device__ inline ushort f2b(float f) {          // f32 -> bf16 bits, RNE
    unsigned u = __float_as_uint(f);
    u += 0x7FFFu + ((u >> 16) & 1u);
    return (ushort)(u >> 16);
}
__device__ inline float b2f(ushort b) {          // bf16 bits -> f32 (exact)
    return __uint_as_float(((unsigned)b) << 16);
}

__device__ inline void load_lds16(const ushort* g, ushort* l) {
    __builtin_amdgcn_global_load_lds(
        (const __attribute__((address_space(1))) unsigned*)g,
        (__attribute__((address_space(3))) unsigned*)l, 16, 0, 0);
}

// ---------- conversions / weight prep ----------
__global__ void conv_bf16(const float* __restrict__ in, ushort* __restrict__ out, int n4) {
    int i = blockIdx.x * blockDim.x + threadIdx.x;
    if (i >= n4) return;
    float4 v = ((const float4*)in)[i];
    ushort4 o;
    o.x = f2b(v.x); o.y = f2b(v.y); o.z = f2b(v.z); o.w = f2b(v.w);
    ((ushort4*)out)[i] = o;
}

// blocks 0..767:   WTq[col][k] = bf16(W_qkv[k][col])           (W_qkv is [256][768])
// blocks 768..1023: WTo[col][c'] = bf16(W_out[pi(c')][col]),   pi(c') = (c'&31)*8 + (c'>>5)
// (absorbs the head-transpose of the attention output into W_out's rows)
__global__ void transpose_w(const float* __restrict__ Wq, const float* __restrict__ Wo,
                            ushort* __restrict__ WTq, ushort* __restrict__ WTo) {
    int b = blockIdx.x;
    int t = threadIdx.x;          // 0..255
    if (b < 768) {
        WTq[(size_t)b * 256 + t] = f2b(Wq[(size_t)t * 768 + b]);
    } else {
        int col = b - 768;        // 0..255
        int c   = ((t & 31) * 8) + (t >> 5);
        WTo[(size_t)col * 256 + t] = f2b(Wo[(size_t)c * 256 + col]);
    }
}

// ---------- MFMA GEMM: C = A[M x 256] * BT[Ncols x 256]^T + bias ----------
// 128x128 tile, BK=32, 4 waves, 16x16x32 bf16 MFMA, global_load_lds width-16.
// MODE 0: Cf[row*256+col] = v  (f32, GEMM2 -> out)
// MODE 1: col<256   -> qb bf16 [row*256+col]
//         col>=256  -> kv bf16 interleaved: k dim d -> (d>>2)*8+(d&3),
//                                           v dim d -> (d>>2)*8+4+(d&3)
template<int MODE>
__global__ __launch_bounds__(256)
void gemm_mfma(const ushort* __restrict__ A,
               const ushort* __restrict__ BT,
               const float*  __restrict__ bias,
               float* __restrict__ Cf,
               ushort* __restrict__ qb, ushort* __restrict__ kv,
               int M) {
    __shared__ ushort As[128 * 32];
    __shared__ ushort Bs[128 * 32];
    const int tid  = threadIdx.x;
    const int wid  = tid >> 6;
    const int lane = tid & 63;
    const int l15  = lane & 15, l4 = lane >> 4;
    const int wr = wid >> 1, wc = wid & 1;
    const int blockRow = blockIdx.x * 128;
    const int blockCol = blockIdx.y * 128;

    f32x4 acc[4][4] = {};

    for (int k0 = 0; k0 < 256; k0 += 32) {
        #pragma unroll
        for (int t = 0; t < 2; ++t) {
            int c   = t * 256 + wid * 64 + lane;   // 16B-chunk index
            int row = c >> 2, ko = (c & 3) * 8;
            load_lds16(A  + (size_t)(blockRow + row) * 256 + k0 + ko,
                       As + (size_t)(t * 256 + wid * 64) * 8);
            load_lds16(BT + (size_t)(blockCol + row) * 256 + k0 + ko,
                       Bs + (size_t)(t * 256 + wid * 64) * 8);
        }
        __syncthreads();
        bf16x8 af[4], bfr[4];
        #pragma unroll
        for (int m = 0; m < 4; ++m)
            af[m] = *(const bf16x8*)&As[(wr * 64 + m * 16 + l15) * 32 + l4 * 8];
        #pragma unroll
        for (int n = 0; n < 4; ++n)
            bfr[n] = *(const bf16x8*)&Bs[(wc * 64 + n * 16 + l15) * 32 + l4 * 8];
        #pragma unroll
        for (int m = 0; m < 4; ++m)
            #pragma unroll
            for (int n = 0; n < 4; ++n)
                acc[m][n] = __builtin_amdgcn_mfma_f32_16x16x32_bf16(af[m], bfr[n], acc[m][n], 0, 0, 0);
        __syncthreads();
    }

    #pragma unroll
    for (int m = 0; m < 4; ++m) {
        #pragma unroll
        for (int r = 0; r < 4; ++r) {
            int row = blockRow + wr * 64 + m * 16 + l4 * 4 + r;
            if (row >= M) continue;
            #pragma unroll
            for (int n = 0; n < 4; ++n) {
                int col = blockCol + wc * 64 + n * 16 + l15;
                float v = acc[m][n][r] + bias[col];
                if (MODE == 0) {
                    Cf[(size_t)row * 256 + col] = v;
                } else {
                    ushort b = f2b(v);
                    if (col < 256) {
                        qb[(size_t)row * 256 + col] = b;
                    } else if (col < 512) {
                        int d = col - 256;
                        kv[(size_t)row * 512 + (d >> 2) * 8 + (d & 3)] = b;
                    } else {
                        int d = col - 512;
                        kv[(size_t)row * 512 + (d >> 2) * 8 + 4 + (d & 3)] = b;
                    }
                }
            }
        }
    }
}

// ---------- CSR build ----------
__global__ void count_dst(const int* __restrict__ dst, int* __restrict__ counts, int E) {
    int i = blockIdx.x * blockDim.x + threadIdx.x;
    if (i < E) atomicAdd(&counts[dst[i]], 1);
}

// Single-workgroup exclusive scan, 1024 threads x 4 elements (int4).
__global__ void scan_offsets(const int* __restrict__ counts, int* __restrict__ offsets,
                             int* __restrict__ cursor, int N) {
    __shared__ int wsum[16];
    __shared__ int carry;
    int tid = threadIdx.x;
    int lane = tid & 63;
    int wid = tid >> 6;
    if (tid == 0) carry = 0;
    __syncthreads();
    for (int base = 0; base < N; base += 4096) {
        int i = base + tid * 4;
        int4 c = make_int4(0, 0, 0, 0);
        if (i < N) c = *(const int4*)(counts + i);
        int s = c.x + c.y + c.z + c.w;
        int x = s;
        #pragma unroll
        for (int d = 1; d < 64; d <<= 1) {
            int y = __shfl_up(x, d);
            if (lane >= d) x += y;
        }
        if (lane == 63) wsum[wid] = x;
        __syncthreads();
        if (wid == 0 && lane < 16) {
            int w = wsum[lane];
            #pragma unroll
            for (int d = 1; d < 16; d <<= 1) {
                int y = __shfl_up(w, d);
                if (lane >= d) w += y;
            }
            wsum[lane] = w;
        }
        __syncthreads();
        int pre = carry + (wid ? wsum[wid - 1] : 0) + (x - s);
        if (i < N) {
            int4 o;
            o.x = pre;
            o.y = pre + c.x;
            o.z = o.y + c.y;
            o.w = o.z + c.z;
            *(int4*)(offsets + i) = o;
            *(int4*)(cursor + i) = o;
        }
        int total = wsum[15];
        __syncthreads();
        if (tid == 0) carry += total;
        __syncthreads();
    }
    if (tid == 0) offsets[N] = carry;
}

__global__ void scatter_edges(const int* __restrict__ src, const int* __restrict__ dst,
                              int* __restrict__ cursor, ushort* __restrict__ csr_src, int E) {
    int i = blockIdx.x * blockDim.x + threadIdx.x;
    if (i < E) {
        int d = dst[i];
        int pos = atomicAdd(&cursor[d], 1);
        csr_src[pos] = (ushort)src[i];
    }
}

// ---------- per-node attention: one wave per dst node ----------
// lane covers dims lane*4..+3 (head=lane>>3). kv interleaved: one 16B load
// gives {k0..k3, v0..v3}. Explicit 8-edge load phase (8 gathers in flight),
// 2 accumulator chains. Explicit scalars ONLY — no private arrays (round-5
// lesson: compiler demotes them to LDS, 64KB/block, occupancy collapse).
__global__ void node_attn(const ushort* __restrict__ qb,
                          const ushort* __restrict__ kv,
                          const int* __restrict__ offsets,
                          const ushort* __restrict__ csr_src,
                          ushort* hbuf,
                          int N) {
    int wid = threadIdx.x >> 6, lane = threadIdx.x & 63;
    int n = blockIdx.x * 4 + wid;
    if (n >= N) return;
    int beg = offsets[n], end = offsets[n + 1];
    ushort4 qu = *(const ushort4*)(qb + (size_t)n * 256 + lane * 4);
    float qx = b2f(qu.x), qy = b2f(qu.y), qz = b2f(qu.z), qw = b2f(qu.w);

    float ax0 = 0.f, ay0 = 0.f, az0 = 0.f, aw0 = 0.f, den0 = 0.f;
    float ax1 = 0.f, ay1 = 0.f, az1 = 0.f, aw1 = 0.f, den1 = 0.f;
    int i = beg;
    #pragma unroll 1
    for (; i + 8 <= end; i += 8) {
        int s0 = csr_src[i], s1 = csr_src[i + 1], s2 = csr_src[i + 2], s3 = csr_src[i + 3];
        int s4 = csr_src[i + 4], s5 = csr_src[i + 5], s6 = csr_src[i + 6], s7 = csr_src[i + 7];
        ushort8 u0 = *(const ushort8*)(kv + (size_t)s0 * 512 + lane * 8);
        ushort8 u1 = *(const ushort8*)(kv + (size_t)s1 * 512 + lane * 8);
        ushort8 u2 = *(const ushort8*)(kv + (size_t)s2 * 512 + lane * 8);
        ushort8 u3 = *(const ushort8*)(kv + (size_t)s3 * 512 + lane * 8);
        ushort8 u4 = *(const ushort8*)(kv + (size_t)s4 * 512 + lane * 8);
        ushort8 u5 = *(const ushort8*)(kv + (size_t)s5 * 512 + lane * 8);
        ushort8 u6 = *(const ushort8*)(kv + (size_t)s6 * 512 + lane * 8);
        ushort8 u7 = *(const ushort8*)(kv + (size_t)s7 * 512 + lane * 8);
        float p0 = qx * b2f(u0[0]) + qy * b2f(u0[1]) + qz * b2f(u0[2]) + qw * b2f(u0[3]);
        float p1 = qx * b2f(u1[0]) + qy * b2f(u1[1]) + qz * b2f(u1[2]) + qw * b2f(u1[3]);
        float p2 = qx * b2f(u2[0]) + qy * b2f(u2[1]) + qz * b2f(u2[2]) + qw * b2f(u2[3]);
        float p3 = qx * b2f(u3[0]) + qy * b2f(u3[1]) + qz * b2f(u3[2]) + qw * b2f(u3[3]);
        float p4 = qx * b2f(u4[0]) + qy * b2f(u4[1]) + qz * b2f(u4[2]) + qw * b2f(u4[3]);
        float p5 = qx * b2f(u5[0]) + qy * b2f(u5[1]) + qz * b2f(u5[2]) + qw * b2f(u5[3]);
        float p6 = qx * b2f(u6[0]) + qy * b2f(u6[1]) + qz * b2f(u6[2]) + qw * b2f(u6[3]);
        float p7 = qx * b2f(u7[0]) + qy * b2f(u7[1]) + qz * b2f(u7[2]) + qw * b2f(u7[3]);
        p0 += __shfl_xor(p0, 1); p1 += __shfl_xor(p1, 1); p2 += __shfl_xor(p2, 1); p3 += __shfl_xor(p3, 1);
        p4 += __shfl_xor(p4, 1); p5 += __shfl_xor(p5, 1); p6 += __shfl_xor(p6, 1); p7 += __shfl_xor(p7, 1);
        p0 += __shfl_xor(p0, 2); p1 += __shfl_xor(p1, 2); p2 += __shfl_xor(p2, 2); p3 += __shfl_xor(p3, 2);
        p4 += __shfl_xor(p4, 2); p5 += __shfl_xor(p5, 2); p6 += __shfl_xor(p6, 2); p7 += __shfl_xor(p7, 2);
        p0 += __shfl_xor(p0, 4); p1 += __shfl_xor(p1, 4); p2 += __shfl_xor(p2, 4); p3 += __shfl_xor(p3, 4);
        p4 += __shfl_xor(p4, 4); p5 += __shfl_xor(p5, 4); p6 += __shfl_xor(p6, 4); p7 += __shfl_xor(p7, 4);
        float sc0 = __expf(p0 * SCALE), sc1 = __expf(p1 * SCALE);
        float sc2 = __expf(p2 * SCALE), sc3 = __expf(p3 * SCALE);
        float sc4 = __expf(p4 * SCALE), sc5 = __expf(p5 * SCALE);
        float sc6 = __expf(p6 * SCALE), sc7 = __expf(p7 * SCALE);
        den0 += (sc0 + sc2) + (sc4 + sc6);
        den1 += (sc1 + sc3) + (sc5 + sc7);
        ax0 += sc0 * b2f(u0[4]) + sc2 * b2f(u2[4]) + sc4 * b2f(u4[4]) + sc6 * b2f(u6[4]);
        ay0 += sc0 * b2f(u0[5]) + sc2 * b2f(u2[5]) + sc4 * b2f(u4[5]) + sc6 * b2f(u6[5]);
        az0 += sc0 * b2f(u0[6]) + sc2 * b2f(u2[6]) + sc4 * b2f(u4[6]) + sc6 * b2f(u6[6]);
        aw0 += sc0 * b2f(u0[7]) + sc2 * b2f(u2[7]) + sc4 * b2f(u4[7]) + sc6 * b2f(u6[7]);
        ax1 += sc1 * b2f(u1[4]) + sc3 * b2f(u3[4]) + sc5 * b2f(u5[4]) + sc7 * b2f(u7[4]);
        ay1 += sc1 * b2f(u1[5]) + sc3 * b2f(u3[5]) + sc5 * b2f(u5[5]) + sc7 * b2f(u7[5]);
        az1 += sc1 * b2f(u1[6]) + sc3 * b2f(u3[6]) + sc5 * b2f(u5[6]) + sc7 * b2f(u7[6]);
        aw1 += sc1 * b2f(u1[7]) + sc3 * b2f(u3[7]) + sc5 * b2f(u5[7]) + sc7 * b2f(u7[7]);
    }
    #pragma unroll 1
    for (; i + 4 <= end; i += 4) {
        int s0 = csr_src[i], s1 = csr_src[i + 1], s2 = csr_src[i + 2], s3 = csr_src[i + 3];
        ushort8 u0 = *(const ushort8*)(kv + (size_t)s0 * 512 + lane * 8);
        ushort8 u1 = *(const ushort8*)(kv + (size_t)s1 * 512 + lane * 8);
        ushort8 u2 = *(const ushort8*)(kv + (size_t)s2 * 512 + lane * 8);
        ushort8 u3 = *(const ushort8*)(kv + (size_t)s3 * 512 + lane * 8);
        float p0 = qx * b2f(u0[0]) + qy * b2f(u0[1]) + qz * b2f(u0[2]) + qw * b2f(u0[3]);
        float p1 = qx * b2f(u1[0]) + qy * b2f(u1[1]) + qz * b2f(u1[2]) + qw * b2f(u1[3]);
        float p2 = qx * b2f(u2[0]) + qy * b2f(u2[1]) + qz * b2f(u2[2]) + qw * b2f(u2[3]);
        float p3 = qx * b2f(u3[0]) + qy * b2f(u3[1]) + qz * b2f(u3[2]) + qw * b2f(u3[3]);
        p0 += __shfl_xor(p0, 1); p1 += __shfl_xor(p1, 1); p2 += __shfl_xor(p2, 1); p3 += __shfl_xor(p3, 1);
        p0 += __shfl_xor(p0, 2); p1 += __shfl_xor(p1, 2); p2 += __shfl_xor(p2, 2); p3 += __shfl_xor(p3, 2);
        p0 += __shfl_xor(p0, 4); p1 += __shfl_xor(p1, 4); p2 += __shfl_xor(p2, 4); p3 += __shfl_xor(p3, 4);
        float sc0 = __expf(p0 * SCALE), sc1 = __expf(p1 * SCALE);
        float sc2 = __expf(p2 * SCALE), sc3 = __expf(p3 * SCALE);
        den0 += sc0 + sc2;
        den1 += sc1 + sc3;
        ax0 += sc0 * b2f(u0[4]) + sc2 * b2f(u2[4]);
        ay0 += sc0 * b2f(u0[5]) + sc2 * b2f(u2[5]);
        az0 += sc0 * b2f(u0[6]) + sc2 * b2f(u2[6]);
        aw0 += sc0 * b2f(u0[7]) + sc2 * b2f(u2[7]);
        ax1 += sc1 * b2f(u1[4]) + sc3 * b2f(u3[4]);
        ay1 += sc1 * b2f(u1[5]) + sc3 * b2f(u3[5]);
        az1 += sc1 * b2f(u1[6]) + sc3 * b2f(u3[6]);
        aw1 += sc1 * b2f(u1[7]) + sc3 * b2f(u3[7]);
    }
    #pragma unroll 1
    for (; i < end; ++i) {
        int s0 = csr_src[i];
        ushort8 u0 = *(const ushort8*)(kv + (size_t)s0 * 512 + lane * 8);
        float p0 = qx * b2f(u0[0]) + qy * b2f(u0[1]) + qz * b2f(u0[2]) + qw * b2f(u0[3]);
        p0 += __shfl_xor(p0, 1);
        p0 += __shfl_xor(p0, 2);
        p0 += __shfl_xor(p0, 4);
        float sc0 = __expf(p0 * SCALE);
        den0 += sc0;
        ax0 += sc0 * b2f(u0[4]); ay0 += sc0 * b2f(u0[5]);
        az0 += sc0 * b2f(u0[6]); aw0 += sc0 * b2f(u0[7]);
    }
    float den = den0 + den1;
    float inv = (end > beg) ? (1.0f / den) : 0.f;
    int head = lane >> 3;
    int d0 = (lane & 7) * 4;
    const ushort* hr = hbuf + (size_t)n * 256;
    float r0 = b2f(hr[(d0 + 0) * 8 + head]);
    float r1 = b2f(hr[(d0 + 1) * 8 + head]);
    float r2 = b2f(hr[(d0 + 2) * 8 + head]);
    float r3 = b2f(hr[(d0 + 3) * 8 + head]);
    ushort4 o;
    o.x = f2b((ax0 + ax1) * inv + r0);
    o.y = f2b((ay0 + ay1) * inv + r1);
    o.z = f2b((az0 + az1) * inv + r2);
    o.w = f2b((aw0 + aw1) * inv + r3);
    *(ushort4*)(hbuf + (size_t)n * 256 + lane * 4) = o;
}

extern "C" void kernel_launch(void* const* d_in, const int* in_sizes, int n_in,
                              void* d_out, int out_size, void* d_ws, size_t ws_size,
                              hipStream_t stream) {
    const float* h     = (const float*)d_in[0];
    const int*   src   = (const int*)d_in[1];
    const int*   dst   = (const int*)d_in[2];
    const float* W_qkv = (const float*)d_in[3];
    const float* b_qkv = (const float*)d_in[4];
    const float* W_out = (const float*)d_in[5];
    const float* b_out = (const float*)d_in[6];
    float* out = (float*)d_out;

    int N = in_sizes[0] / 256;
    int E = in_sizes[1];
    int Mpad = (N + 127) & ~127;
    int No   = (N + 16) & ~15;          // padded int stride, keeps int4 alignment

    ushort* qb   = (ushort*)d_ws;                      // Mpad*256 bf16
    ushort* kv   = qb + (size_t)Mpad * 256;            // Mpad*512 bf16 (interleaved)
    ushort* Abf  = kv + (size_t)Mpad * 512;            // Mpad*256 bf16 (h, then h2)
    ushort* WTq  = Abf + (size_t)Mpad * 256;           // 768*256
    ushort* WTo  = WTq + 768 * 256;                    // 256*256
    int* counts  = (int*)(WTo + 256 * 256);            // No
    int* offsets = counts + No;                        // No+1 (uses N+1)
    int* cursor  = offsets + No;                       // No
    ushort* csr_src = (ushort*)(cursor + No);          // E (ushort: N < 65536)

    hipMemsetAsync(counts, 0, (size_t)No * sizeof(int), stream);

    conv_bf16<<<(N * 64 + 255) / 256, 256, 0, stream>>>(h, Abf, N * 64);
    transpose_w<<<1024, 256, 0, stream>>>(W_qkv, W_out, WTq, WTo);

    count_dst<<<(E + 255) / 256, 256, 0, stream>>>(dst, counts, E);
    scan_offsets<<<1, 1024, 0, stream>>>(counts, offsets, cursor, N);
    scatter_edges<<<(E + 255) / 256, 256, 0, stream>>>(src, dst, cursor, csr_src, E);

    dim3 g1(Mpad / 128, 6);
    gemm_mfma<1><<<g1, 256, 0, stream>>>(Abf, WTq, b_qkv, nullptr, qb, kv, N);

    node_attn<<<(N + 3) / 4, 256, 0, stream>>>(qb, kv, offsets, csr_src, Abf, N);

    dim3 g2(Mpad / 128, 2);
    gemm_mfma<0><<<g2, 256, 0, stream>>>(Abf, WTo, b_out, out, nullptr, nullptr, N);
}

// Round 7
// 311.957 us; speedup vs baseline: 1.4429x; 1.0891x over previous
//
#include <hip/hip_runtime.h>
#include <hip/hip_bf16.h>

#define NHEAD 8
#define SCALE 0.17677669529663687f      // 32^-0.5
#define EXSCALE 0.2551149170424794f     // SCALE * log2(e): one mul + v_exp_f32

typedef __attribute__((ext_vector_type(8))) short bf16x8;
typedef __attribute__((ext_vector_type(4))) float f32x4;
typedef __attribute__((ext_vector_type(8))) unsigned short ushort8;

__device__ inline ushort f2b(float f) {          // f32 -> bf16 bits, RNE
    unsigned u = __float_as_uint(f);
    u += 0x7FFFu + ((u >> 16) & 1u);
    return (ushort)(u >> 16);
}
__device__ inline float b2f(ushort b) {          // bf16 bits -> f32 (exact)
    return __uint_as_float(((unsigned)b) << 16);
}

__device__ inline void load_lds16(const ushort* g, ushort* l) {
    __builtin_amdgcn_global_load_lds(
        (const __attribute__((address_space(1))) unsigned*)g,
        (__attribute__((address_space(3))) unsigned*)l, 16, 0, 0);
}

// ---------- fused prep: conv h->bf16 | transpose weights | count dst ----------
// blocks [0,B0): conv_bf16 (float4 per thread)
// blocks [B0,B0+1024): weight transpose (768 for W_qkv, 256 for W_out w/ head-perm)
// blocks [B0+1024, ...): count_dst, 4 edges/thread
__global__ void prep(const float* __restrict__ h, ushort* __restrict__ Abf, int n4,
                     const float* __restrict__ Wq, const float* __restrict__ Wo,
                     ushort* __restrict__ WTq, ushort* __restrict__ WTo,
                     const int* __restrict__ dst, int* __restrict__ counts, int E,
                     int B0, int B1) {
    int bid = blockIdx.x, tid = threadIdx.x;
    if (bid < B0) {
        int i = bid * 256 + tid;
        if (i < n4) {
            float4 v = ((const float4*)h)[i];
            ushort4 o;
            o.x = f2b(v.x); o.y = f2b(v.y); o.z = f2b(v.z); o.w = f2b(v.w);
            ((ushort4*)Abf)[i] = o;
        }
    } else if (bid < B1) {
        int b = bid - B0;
        if (b < 768) {
            WTq[(size_t)b * 256 + tid] = f2b(Wq[(size_t)tid * 768 + b]);
        } else {
            int col = b - 768;
            int c   = ((tid & 31) * 8) + (tid >> 5);   // absorb head-transpose
            WTo[(size_t)col * 256 + tid] = f2b(Wo[(size_t)c * 256 + col]);
        }
    } else {
        int i = (bid - B1) * 1024 + tid * 4;
        if (i + 3 < E) {
            int4 d4 = *(const int4*)(dst + i);
            atomicAdd(&counts[d4.x], 1);
            atomicAdd(&counts[d4.y], 1);
            atomicAdd(&counts[d4.z], 1);
            atomicAdd(&counts[d4.w], 1);
        } else {
            for (int t = 0; t < 4; ++t)
                if (i + t < E) atomicAdd(&counts[dst[i + t]], 1);
        }
    }
}

// ---------- 3-kernel scan (replaces single-workgroup serial scan) ----------
__global__ void scanA(const int* __restrict__ counts, int* __restrict__ bsum, int N) {
    __shared__ int ws[16];
    int tid = threadIdx.x, lane = tid & 63, wid = tid >> 6;
    int i = blockIdx.x * 4096 + tid * 4;
    int s = 0;
    if (i < N) { int4 c = *(const int4*)(counts + i); s = c.x + c.y + c.z + c.w; }
    #pragma unroll
    for (int d = 1; d < 64; d <<= 1) s += __shfl_xor(s, d);
    if (lane == 0) ws[wid] = s;
    __syncthreads();
    if (tid < 16) {
        int v = ws[tid];
        #pragma unroll
        for (int d = 1; d < 16; d <<= 1) v += __shfl_xor(v, d);
        if (tid == 0) bsum[blockIdx.x] = v;
    }
}

__global__ void scanB(const int* __restrict__ bsum, int* __restrict__ bbase, int nb,
                      int* __restrict__ offsets, int N, int E) {
    int t = threadIdx.x;      // 64 threads
    int v = (t < nb) ? bsum[t] : 0;
    int x = v;
    #pragma unroll
    for (int d = 1; d < 64; d <<= 1) {
        int y = __shfl_up(x, d);
        if (t >= d) x += y;
    }
    if (t < nb) bbase[t] = x - v;    // exclusive base per block
    if (t == 0) offsets[N] = E;
}

__global__ void scanC(const int* __restrict__ counts, const int* __restrict__ bbase,
                      int* __restrict__ offsets, int* __restrict__ cursor, int N) {
    __shared__ int wsum[16];
    int tid = threadIdx.x, lane = tid & 63, wid = tid >> 6;
    int i = blockIdx.x * 4096 + tid * 4;
    int4 c = make_int4(0, 0, 0, 0);
    if (i < N) c = *(const int4*)(counts + i);
    int s = c.x + c.y + c.z + c.w;
    int x = s;
    #pragma unroll
    for (int d = 1; d < 64; d <<= 1) {
        int y = __shfl_up(x, d);
        if (lane >= d) x += y;
    }
    if (lane == 63) wsum[wid] = x;
    __syncthreads();
    if (wid == 0 && lane < 16) {
        int w = wsum[lane];
        #pragma unroll
        for (int d = 1; d < 16; d <<= 1) {
            int y = __shfl_up(w, d);
            if (lane >= d) w += y;
        }
        wsum[lane] = w;
    }
    __syncthreads();
    int pre = bbase[blockIdx.x] + (wid ? wsum[wid - 1] : 0) + (x - s);
    if (i < N) {
        int4 o;
        o.x = pre;
        o.y = pre + c.x;
        o.z = o.y + c.y;
        o.w = o.z + c.z;
        *(int4*)(offsets + i) = o;
        *(int4*)(cursor + i) = o;
    }
}

__global__ void scatter_edges(const int* __restrict__ src, const int* __restrict__ dst,
                              int* __restrict__ cursor, ushort* __restrict__ csr_src, int E) {
    int i = blockIdx.x * blockDim.x + threadIdx.x;
    if (i < E) {
        int d = dst[i];
        int pos = atomicAdd(&cursor[d], 1);
        csr_src[pos] = (ushort)src[i];
    }
}

// ---------- MFMA GEMM: C = A[M x 256] * BT[Ncols x 256]^T + bias ----------
// 128x128 tile, BK=32, 4 waves, 16x16x32 bf16 MFMA, global_load_lds width-16.
// 1-D grid + m204 bijective XCD swizzle; work order = cols innermost, so each
// XCD runs all NCB col-tiles of a row-block back-to-back (A-tile stays L2-hot,
// B panel is L2-resident per XCD). MODE 0: f32 out. MODE 1: q bf16 + interleaved kv.
template<int MODE>
__global__ __launch_bounds__(256)
void gemm_mfma(const ushort* __restrict__ A,
               const ushort* __restrict__ BT,
               const float*  __restrict__ bias,
               float* __restrict__ Cf,
               ushort* __restrict__ qb, ushort* __restrict__ kv,
               int M, int NCB) {
    __shared__ ushort As[128 * 32];
    __shared__ ushort Bs[128 * 32];
    const int nwg = gridDim.x;
    const int bid = blockIdx.x;
    const int q8 = nwg >> 3, r8 = nwg & 7, xcd = bid & 7, seq = bid >> 3;
    const int wgid = (xcd < r8 ? xcd * (q8 + 1) : r8 * (q8 + 1) + (xcd - r8) * q8) + seq;
    const int blockRow = (wgid / NCB) * 128;
    const int blockCol = (wgid % NCB) * 128;

    const int tid  = threadIdx.x;
    const int wid  = tid >> 6;
    const int lane = tid & 63;
    const int l15  = lane & 15, l4 = lane >> 4;
    const int wr = wid >> 1, wc = wid & 1;

    f32x4 acc[4][4] = {};

    for (int k0 = 0; k0 < 256; k0 += 32) {
        #pragma unroll
        for (int t = 0; t < 2; ++t) {
            int c   = t * 256 + wid * 64 + lane;   // 16B-chunk index
            int row = c >> 2, ko = (c & 3) * 8;
            load_lds16(A  + (size_t)(blockRow + row) * 256 + k0 + ko,
                       As + (size_t)(t * 256 + wid * 64) * 8);
            load_lds16(BT + (size_t)(blockCol + row) * 256 + k0 + ko,
                       Bs + (size_t)(t * 256 + wid * 64) * 8);
        }
        __syncthreads();
        bf16x8 af[4], bfr[4];
        #pragma unroll
        for (int m = 0; m < 4; ++m)
            af[m] = *(const bf16x8*)&As[(wr * 64 + m * 16 + l15) * 32 + l4 * 8];
        #pragma unroll
        for (int n = 0; n < 4; ++n)
            bfr[n] = *(const bf16x8*)&Bs[(wc * 64 + n * 16 + l15) * 32 + l4 * 8];
        #pragma unroll
        for (int m = 0; m < 4; ++m)
            #pragma unroll
            for (int n = 0; n < 4; ++n)
                acc[m][n] = __builtin_amdgcn_mfma_f32_16x16x32_bf16(af[m], bfr[n], acc[m][n], 0, 0, 0);
        __syncthreads();
    }

    #pragma unroll
    for (int m = 0; m < 4; ++m) {
        #pragma unroll
        for (int r = 0; r < 4; ++r) {
            int row = blockRow + wr * 64 + m * 16 + l4 * 4 + r;
            if (row >= M) continue;
            #pragma unroll
            for (int n = 0; n < 4; ++n) {
                int col = blockCol + wc * 64 + n * 16 + l15;
                float v = acc[m][n][r] + bias[col];
                if (MODE == 0) {
                    Cf[(size_t)row * 256 + col] = v;
                } else {
                    ushort b = f2b(v);
                    if (col < 256) {
                        qb[(size_t)row * 256 + col] = b;
                    } else if (col < 512) {
                        int d = col - 256;
                        kv[(size_t)row * 512 + (d >> 2) * 8 + (d & 3)] = b;
                    } else {
                        int d = col - 512;
                        kv[(size_t)row * 512 + (d >> 2) * 8 + 4 + (d & 3)] = b;
                    }
                }
            }
        }
    }
}

// ---------- per-node attention: one wave per dst node ----------
// lane covers dims lane*4..+3 (head=lane>>3). kv interleaved: one 16B load
// gives {k0..k3, v0..v3}. 8/4/1 edge phases, 2 accumulator chains.
// Explicit scalars ONLY (round-5 lesson: private arrays demote to LDS).
__global__ void node_attn(const ushort* __restrict__ qb,
                          const ushort* __restrict__ kv,
                          const int* __restrict__ offsets,
                          const ushort* __restrict__ csr_src,
                          ushort* hbuf,
                          int N) {
    int wid = threadIdx.x >> 6, lane = threadIdx.x & 63;
    int n = blockIdx.x * 4 + wid;
    if (n >= N) return;
    int beg = offsets[n], end = offsets[n + 1];
    ushort4 qu = *(const ushort4*)(qb + (size_t)n * 256 + lane * 4);
    float qx = b2f(qu.x), qy = b2f(qu.y), qz = b2f(qu.z), qw = b2f(qu.w);

    float ax0 = 0.f, ay0 = 0.f, az0 = 0.f, aw0 = 0.f, den0 = 0.f;
    float ax1 = 0.f, ay1 = 0.f, az1 = 0.f, aw1 = 0.f, den1 = 0.f;
    int i = beg;
    #pragma unroll 1
    for (; i + 8 <= end; i += 8) {
        int s0 = csr_src[i], s1 = csr_src[i + 1], s2 = csr_src[i + 2], s3 = csr_src[i + 3];
        int s4 = csr_src[i + 4], s5 = csr_src[i + 5], s6 = csr_src[i + 6], s7 = csr_src[i + 7];
        ushort8 u0 = *(const ushort8*)(kv + (size_t)s0 * 512 + lane * 8);
        ushort8 u1 = *(const ushort8*)(kv + (size_t)s1 * 512 + lane * 8);
        ushort8 u2 = *(const ushort8*)(kv + (size_t)s2 * 512 + lane * 8);
        ushort8 u3 = *(const ushort8*)(kv + (size_t)s3 * 512 + lane * 8);
        ushort8 u4 = *(const ushort8*)(kv + (size_t)s4 * 512 + lane * 8);
        ushort8 u5 = *(const ushort8*)(kv + (size_t)s5 * 512 + lane * 8);
        ushort8 u6 = *(const ushort8*)(kv + (size_t)s6 * 512 + lane * 8);
        ushort8 u7 = *(const ushort8*)(kv + (size_t)s7 * 512 + lane * 8);
        float p0 = qx * b2f(u0[0]) + qy * b2f(u0[1]) + qz * b2f(u0[2]) + qw * b2f(u0[3]);
        float p1 = qx * b2f(u1[0]) + qy * b2f(u1[1]) + qz * b2f(u1[2]) + qw * b2f(u1[3]);
        float p2 = qx * b2f(u2[0]) + qy * b2f(u2[1]) + qz * b2f(u2[2]) + qw * b2f(u2[3]);
        float p3 = qx * b2f(u3[0]) + qy * b2f(u3[1]) + qz * b2f(u3[2]) + qw * b2f(u3[3]);
        float p4 = qx * b2f(u4[0]) + qy * b2f(u4[1]) + qz * b2f(u4[2]) + qw * b2f(u4[3]);
        float p5 = qx * b2f(u5[0]) + qy * b2f(u5[1]) + qz * b2f(u5[2]) + qw * b2f(u5[3]);
        float p6 = qx * b2f(u6[0]) + qy * b2f(u6[1]) + qz * b2f(u6[2]) + qw * b2f(u6[3]);
        float p7 = qx * b2f(u7[0]) + qy * b2f(u7[1]) + qz * b2f(u7[2]) + qw * b2f(u7[3]);
        p0 += __shfl_xor(p0, 1); p1 += __shfl_xor(p1, 1); p2 += __shfl_xor(p2, 1); p3 += __shfl_xor(p3, 1);
        p4 += __shfl_xor(p4, 1); p5 += __shfl_xor(p5, 1); p6 += __shfl_xor(p6, 1); p7 += __shfl_xor(p7, 1);
        p0 += __shfl_xor(p0, 2); p1 += __shfl_xor(p1, 2); p2 += __shfl_xor(p2, 2); p3 += __shfl_xor(p3, 2);
        p4 += __shfl_xor(p4, 2); p5 += __shfl_xor(p5, 2); p6 += __shfl_xor(p6, 2); p7 += __shfl_xor(p7, 2);
        p0 += __shfl_xor(p0, 4); p1 += __shfl_xor(p1, 4); p2 += __shfl_xor(p2, 4); p3 += __shfl_xor(p3, 4);
        p4 += __shfl_xor(p4, 4); p5 += __shfl_xor(p5, 4); p6 += __shfl_xor(p6, 4); p7 += __shfl_xor(p7, 4);
        float sc0 = exp2f(p0 * EXSCALE), sc1 = exp2f(p1 * EXSCALE);
        float sc2 = exp2f(p2 * EXSCALE), sc3 = exp2f(p3 * EXSCALE);
        float sc4 = exp2f(p4 * EXSCALE), sc5 = exp2f(p5 * EXSCALE);
        float sc6 = exp2f(p6 * EXSCALE), sc7 = exp2f(p7 * EXSCALE);
        den0 += (sc0 + sc2) + (sc4 + sc6);
        den1 += (sc1 + sc3) + (sc5 + sc7);
        ax0 += sc0 * b2f(u0[4]) + sc2 * b2f(u2[4]) + sc4 * b2f(u4[4]) + sc6 * b2f(u6[4]);
        ay0 += sc0 * b2f(u0[5]) + sc2 * b2f(u2[5]) + sc4 * b2f(u4[5]) + sc6 * b2f(u6[5]);
        az0 += sc0 * b2f(u0[6]) + sc2 * b2f(u2[6]) + sc4 * b2f(u4[6]) + sc6 * b2f(u6[6]);
        aw0 += sc0 * b2f(u0[7]) + sc2 * b2f(u2[7]) + sc4 * b2f(u4[7]) + sc6 * b2f(u6[7]);
        ax1 += sc1 * b2f(u1[4]) + sc3 * b2f(u3[4]) + sc5 * b2f(u5[4]) + sc7 * b2f(u7[4]);
        ay1 += sc1 * b2f(u1[5]) + sc3 * b2f(u3[5]) + sc5 * b2f(u5[5]) + sc7 * b2f(u7[5]);
        az1 += sc1 * b2f(u1[6]) + sc3 * b2f(u3[6]) + sc5 * b2f(u5[6]) + sc7 * b2f(u7[6]);
        aw1 += sc1 * b2f(u1[7]) + sc3 * b2f(u3[7]) + sc5 * b2f(u5[7]) + sc7 * b2f(u7[7]);
    }
    #pragma unroll 1
    for (; i + 4 <= end; i += 4) {
        int s0 = csr_src[i], s1 = csr_src[i + 1], s2 = csr_src[i + 2], s3 = csr_src[i + 3];
        ushort8 u0 = *(const ushort8*)(kv + (size_t)s0 * 512 + lane * 8);
        ushort8 u1 = *(const ushort8*)(kv + (size_t)s1 * 512 + lane * 8);
        ushort8 u2 = *(const ushort8*)(kv + (size_t)s2 * 512 + lane * 8);
        ushort8 u3 = *(const ushort8*)(kv + (size_t)s3 * 512 + lane * 8);
        float p0 = qx * b2f(u0[0]) + qy * b2f(u0[1]) + qz * b2f(u0[2]) + qw * b2f(u0[3]);
        float p1 = qx * b2f(u1[0]) + qy * b2f(u1[1]) + qz * b2f(u1[2]) + qw * b2f(u1[3]);
        float p2 = qx * b2f(u2[0]) + qy * b2f(u2[1]) + qz * b2f(u2[2]) + qw * b2f(u2[3]);
        float p3 = qx * b2f(u3[0]) + qy * b2f(u3[1]) + qz * b2f(u3[2]) + qw * b2f(u3[3]);
        p0 += __shfl_xor(p0, 1); p1 += __shfl_xor(p1, 1); p2 += __shfl_xor(p2, 1); p3 += __shfl_xor(p3, 1);
        p0 += __shfl_xor(p0, 2); p1 += __shfl_xor(p1, 2); p2 += __shfl_xor(p2, 2); p3 += __shfl_xor(p3, 2);
        p0 += __shfl_xor(p0, 4); p1 += __shfl_xor(p1, 4); p2 += __shfl_xor(p2, 4); p3 += __shfl_xor(p3, 4);
        float sc0 = exp2f(p0 * EXSCALE), sc1 = exp2f(p1 * EXSCALE);
        float sc2 = exp2f(p2 * EXSCALE), sc3 = exp2f(p3 * EXSCALE);
        den0 += sc0 + sc2;
        den1 += sc1 + sc3;
        ax0 += sc0 * b2f(u0[4]) + sc2 * b2f(u2[4]);
        ay0 += sc0 * b2f(u0[5]) + sc2 * b2f(u2[5]);
        az0 += sc0 * b2f(u0[6]) + sc2 * b2f(u2[6]);
        aw0 += sc0 * b2f(u0[7]) + sc2 * b2f(u2[7]);
        ax1 += sc1 * b2f(u1[4]) + sc3 * b2f(u3[4]);
        ay1 += sc1 * b2f(u1[5]) + sc3 * b2f(u3[5]);
        az1 += sc1 * b2f(u1[6]) + sc3 * b2f(u3[6]);
        aw1 += sc1 * b2f(u1[7]) + sc3 * b2f(u3[7]);
    }
    #pragma unroll 1
    for (; i < end; ++i) {
        int s0 = csr_src[i];
        ushort8 u0 = *(const ushort8*)(kv + (size_t)s0 * 512 + lane * 8);
        float p0 = qx * b2f(u0[0]) + qy * b2f(u0[1]) + qz * b2f(u0[2]) + qw * b2f(u0[3]);
        p0 += __shfl_xor(p0, 1);
        p0 += __shfl_xor(p0, 2);
        p0 += __shfl_xor(p0, 4);
        float sc0 = exp2f(p0 * EXSCALE);
        den0 += sc0;
        ax0 += sc0 * b2f(u0[4]); ay0 += sc0 * b2f(u0[5]);
        az0 += sc0 * b2f(u0[6]); aw0 += sc0 * b2f(u0[7]);
    }
    float den = den0 + den1;
    float inv = (end > beg) ? (1.0f / den) : 0.f;
    int head = lane >> 3;
    int d0 = (lane & 7) * 4;
    const ushort* hr = hbuf + (size_t)n * 256;
    float r0 = b2f(hr[(d0 + 0) * 8 + head]);
    float r1 = b2f(hr[(d0 + 1) * 8 + head]);
    float r2 = b2f(hr[(d0 + 2) * 8 + head]);
    float r3 = b2f(hr[(d0 + 3) * 8 + head]);
    ushort4 o;
    o.x = f2b((ax0 + ax1) * inv + r0);
    o.y = f2b((ay0 + ay1) * inv + r1);
    o.z = f2b((az0 + az1) * inv + r2);
    o.w = f2b((aw0 + aw1) * inv + r3);
    *(ushort4*)(hbuf + (size_t)n * 256 + lane * 4) = o;
}

extern "C" void kernel_launch(void* const* d_in, const int* in_sizes, int n_in,
                              void* d_out, int out_size, void* d_ws, size_t ws_size,
                              hipStream_t stream) {
    const float* h     = (const float*)d_in[0];
    const int*   src   = (const int*)d_in[1];
    const int*   dst   = (const int*)d_in[2];
    const float* W_qkv = (const float*)d_in[3];
    const float* b_qkv = (const float*)d_in[4];
    const float* W_out = (const float*)d_in[5];
    const float* b_out = (const float*)d_in[6];
    float* out = (float*)d_out;

    int N = in_sizes[0] / 256;
    int E = in_sizes[1];
    int Mpad = (N + 127) & ~127;
    int No   = (N + 16) & ~15;          // padded int stride, int4 alignment

    ushort* qb   = (ushort*)d_ws;                      // Mpad*256 bf16
    ushort* kv   = qb + (size_t)Mpad * 256;            // Mpad*512 bf16 (interleaved)
    ushort* Abf  = kv + (size_t)Mpad * 512;            // Mpad*256 bf16 (h, then h2)
    ushort* WTq  = Abf + (size_t)Mpad * 256;           // 768*256
    ushort* WTo  = WTq + 768 * 256;                    // 256*256
    int* counts  = (int*)(WTo + 256 * 256);            // No
    int* offsets = counts + No;                        // No+1
    int* cursor  = offsets + No;                       // No
    int* bsum    = cursor + No;                        // 32
    int* bbase   = bsum + 32;                          // 32
    ushort* csr_src = (ushort*)(bbase + 32);           // E (ushort: N < 65536)

    hipMemsetAsync(counts, 0, (size_t)No * sizeof(int), stream);

    int n4 = N * 64;
    int B0 = (n4 + 255) / 256;
    int B1 = B0 + 1024;
    int BC = (E + 1023) / 1024;
    prep<<<B1 + BC, 256, 0, stream>>>(h, Abf, n4, W_qkv, W_out, WTq, WTo,
                                      dst, counts, E, B0, B1);

    int nb = (N + 4095) / 4096;
    scanA<<<nb, 1024, 0, stream>>>(counts, bsum, N);
    scanB<<<1, 64, 0, stream>>>(bsum, bbase, nb, offsets, N, E);
    scanC<<<nb, 1024, 0, stream>>>(counts, bbase, offsets, cursor, N);
    scatter_edges<<<(E + 255) / 256, 256, 0, stream>>>(src, dst, cursor, csr_src, E);

    int nrb = Mpad / 128;
    gemm_mfma<1><<<nrb * 6, 256, 0, stream>>>(Abf, WTq, b_qkv, nullptr, qb, kv, N, 6);

    node_attn<<<(N + 3) / 4, 256, 0, stream>>>(qb, kv, offsets, csr_src, Abf, N);

    gemm_mfma<0><<<nrb * 2, 256, 0, stream>>>(Abf, WTo, b_out, out, nullptr, nullptr, N, 2);
}

// Round 8
// 260.126 us; speedup vs baseline: 1.7305x; 1.1993x over previous
//
#include <hip/hip_runtime.h>
#include <hip/hip_bf16.h>

#define NHEAD 8
#define SCALE 0.17677669529663687f      // 32^-0.5
#define EXSCALE 0.2551149170424794f     // SCALE * log2(e): one mul + v_exp_f32

typedef __attribute__((ext_vector_type(8))) short bf16x8;
typedef __attribute__((ext_vector_type(4))) float f32x4;
typedef __attribute__((ext_vector_type(2))) float f32x2;
typedef __attribute__((ext_vector_type(8))) unsigned short ushort8;

__device__ inline ushort f2b(float f) {          // f32 -> bf16 bits, RNE
    unsigned u = __float_as_uint(f);
    u += 0x7FFFu + ((u >> 16) & 1u);
    return (ushort)(u >> 16);
}
__device__ inline float b2f(ushort b) {          // bf16 bits -> f32 (exact)
    return __uint_as_float(((unsigned)b) << 16);
}
__device__ inline unsigned char f2fp8(float f) { // f32 -> OCP e4m3 (RNE, sat)
    return (unsigned char)(__builtin_amdgcn_cvt_pk_fp8_f32(f, f, 0u, false) & 0xFFu);
}

__device__ inline void load_lds16(const ushort* g, ushort* l) {
    __builtin_amdgcn_global_load_lds(
        (const __attribute__((address_space(1))) unsigned*)g,
        (__attribute__((address_space(3))) unsigned*)l, 16, 0, 0);
}

// ---------- fused prep: conv h->bf16 | transpose weights | count dst ----------
__global__ void prep(const float* __restrict__ h, ushort* __restrict__ Abf, int n4,
                     const float* __restrict__ Wq, const float* __restrict__ Wo,
                     ushort* __restrict__ WTq, ushort* __restrict__ WTo,
                     const int* __restrict__ dst, int* __restrict__ counts, int E,
                     int B0, int B1) {
    int bid = blockIdx.x, tid = threadIdx.x;
    if (bid < B0) {
        int i = bid * 256 + tid;
        if (i < n4) {
            float4 v = ((const float4*)h)[i];
            ushort4 o;
            o.x = f2b(v.x); o.y = f2b(v.y); o.z = f2b(v.z); o.w = f2b(v.w);
            ((ushort4*)Abf)[i] = o;
        }
    } else if (bid < B1) {
        int b = bid - B0;
        if (b < 768) {
            WTq[(size_t)b * 256 + tid] = f2b(Wq[(size_t)tid * 768 + b]);
        } else {
            int col = b - 768;
            int c   = ((tid & 31) * 8) + (tid >> 5);   // absorb head-transpose
            WTo[(size_t)col * 256 + tid] = f2b(Wo[(size_t)c * 256 + col]);
        }
    } else {
        int i = (bid - B1) * 1024 + tid * 4;
        if (i + 3 < E) {
            int4 d4 = *(const int4*)(dst + i);
            atomicAdd(&counts[d4.x], 1);
            atomicAdd(&counts[d4.y], 1);
            atomicAdd(&counts[d4.z], 1);
            atomicAdd(&counts[d4.w], 1);
        } else {
            for (int t = 0; t < 4; ++t)
                if (i + t < E) atomicAdd(&counts[dst[i + t]], 1);
        }
    }
}

// ---------- 3-kernel scan ----------
__global__ void scanA(const int* __restrict__ counts, int* __restrict__ bsum, int N) {
    __shared__ int ws[16];
    int tid = threadIdx.x, lane = tid & 63, wid = tid >> 6;
    int i = blockIdx.x * 4096 + tid * 4;
    int s = 0;
    if (i < N) { int4 c = *(const int4*)(counts + i); s = c.x + c.y + c.z + c.w; }
    #pragma unroll
    for (int d = 1; d < 64; d <<= 1) s += __shfl_xor(s, d);
    if (lane == 0) ws[wid] = s;
    __syncthreads();
    if (tid < 16) {
        int v = ws[tid];
        #pragma unroll
        for (int d = 1; d < 16; d <<= 1) v += __shfl_xor(v, d);
        if (tid == 0) bsum[blockIdx.x] = v;
    }
}

__global__ void scanB(const int* __restrict__ bsum, int* __restrict__ bbase, int nb,
                      int* __restrict__ offsets, int N, int E) {
    int t = threadIdx.x;      // 64 threads
    int v = (t < nb) ? bsum[t] : 0;
    int x = v;
    #pragma unroll
    for (int d = 1; d < 64; d <<= 1) {
        int y = __shfl_up(x, d);
        if (t >= d) x += y;
    }
    if (t < nb) bbase[t] = x - v;
    if (t == 0) offsets[N] = E;
}

__global__ void scanC(const int* __restrict__ counts, const int* __restrict__ bbase,
                      int* __restrict__ offsets, int* __restrict__ cursor, int N) {
    __shared__ int wsum[16];
    int tid = threadIdx.x, lane = tid & 63, wid = tid >> 6;
    int i = blockIdx.x * 4096 + tid * 4;
    int4 c = make_int4(0, 0, 0, 0);
    if (i < N) c = *(const int4*)(counts + i);
    int s = c.x + c.y + c.z + c.w;
    int x = s;
    #pragma unroll
    for (int d = 1; d < 64; d <<= 1) {
        int y = __shfl_up(x, d);
        if (lane >= d) x += y;
    }
    if (lane == 63) wsum[wid] = x;
    __syncthreads();
    if (wid == 0 && lane < 16) {
        int w = wsum[lane];
        #pragma unroll
        for (int d = 1; d < 16; d <<= 1) {
            int y = __shfl_up(w, d);
            if (lane >= d) w += y;
        }
        wsum[lane] = w;
    }
    __syncthreads();
    int pre = bbase[blockIdx.x] + (wid ? wsum[wid - 1] : 0) + (x - s);
    if (i < N) {
        int4 o;
        o.x = pre;
        o.y = pre + c.x;
        o.z = o.y + c.y;
        o.w = o.z + c.z;
        *(int4*)(offsets + i) = o;
        *(int4*)(cursor + i) = o;
    }
}

__global__ void scatter_edges(const int* __restrict__ src, const int* __restrict__ dst,
                              int* __restrict__ cursor, ushort* __restrict__ csr_src, int E) {
    int i = blockIdx.x * blockDim.x + threadIdx.x;
    if (i < E) {
        int d = dst[i];
        int pos = atomicAdd(&cursor[d], 1);
        csr_src[pos] = (ushort)src[i];
    }
}

// ---------- MFMA GEMM: C = A[M x 256] * BT[Ncols x 256]^T + bias ----------
// 128x128 tile, BK=32, 4 waves, 16x16x32 bf16 MFMA, global_load_lds width-16.
// 1-D grid + bijective XCD swizzle, cols innermost per XCD (A-tile L2-hot).
// MODE 0: f32 out. MODE 1: q bf16 + interleaved fp8 kv:
//   k dim d -> byte (d>>2)*8+(d&3); v dim d -> byte (d>>2)*8+4+(d&3)
template<int MODE>
__global__ __launch_bounds__(256)
void gemm_mfma(const ushort* __restrict__ A,
               const ushort* __restrict__ BT,
               const float*  __restrict__ bias,
               float* __restrict__ Cf,
               ushort* __restrict__ qb, unsigned char* __restrict__ kv8,
               int M, int NCB) {
    __shared__ ushort As[128 * 32];
    __shared__ ushort Bs[128 * 32];
    const int nwg = gridDim.x;
    const int bid = blockIdx.x;
    const int q8 = nwg >> 3, r8 = nwg & 7, xcd = bid & 7, seq = bid >> 3;
    const int wgid = (xcd < r8 ? xcd * (q8 + 1) : r8 * (q8 + 1) + (xcd - r8) * q8) + seq;
    const int blockRow = (wgid / NCB) * 128;
    const int blockCol = (wgid % NCB) * 128;

    const int tid  = threadIdx.x;
    const int wid  = tid >> 6;
    const int lane = tid & 63;
    const int l15  = lane & 15, l4 = lane >> 4;
    const int wr = wid >> 1, wc = wid & 1;

    f32x4 acc[4][4] = {};

    for (int k0 = 0; k0 < 256; k0 += 32) {
        #pragma unroll
        for (int t = 0; t < 2; ++t) {
            int c   = t * 256 + wid * 64 + lane;   // 16B-chunk index
            int row = c >> 2, ko = (c & 3) * 8;
            load_lds16(A  + (size_t)(blockRow + row) * 256 + k0 + ko,
                       As + (size_t)(t * 256 + wid * 64) * 8);
            load_lds16(BT + (size_t)(blockCol + row) * 256 + k0 + ko,
                       Bs + (size_t)(t * 256 + wid * 64) * 8);
        }
        __syncthreads();
        bf16x8 af[4], bfr[4];
        #pragma unroll
        for (int m = 0; m < 4; ++m)
            af[m] = *(const bf16x8*)&As[(wr * 64 + m * 16 + l15) * 32 + l4 * 8];
        #pragma unroll
        for (int n = 0; n < 4; ++n)
            bfr[n] = *(const bf16x8*)&Bs[(wc * 64 + n * 16 + l15) * 32 + l4 * 8];
        #pragma unroll
        for (int m = 0; m < 4; ++m)
            #pragma unroll
            for (int n = 0; n < 4; ++n)
                acc[m][n] = __builtin_amdgcn_mfma_f32_16x16x32_bf16(af[m], bfr[n], acc[m][n], 0, 0, 0);
        __syncthreads();
    }

    #pragma unroll
    for (int m = 0; m < 4; ++m) {
        #pragma unroll
        for (int r = 0; r < 4; ++r) {
            int row = blockRow + wr * 64 + m * 16 + l4 * 4 + r;
            if (row >= M) continue;
            #pragma unroll
            for (int n = 0; n < 4; ++n) {
                int col = blockCol + wc * 64 + n * 16 + l15;
                float v = acc[m][n][r] + bias[col];
                if (MODE == 0) {
                    Cf[(size_t)row * 256 + col] = v;
                } else {
                    if (col < 256) {
                        qb[(size_t)row * 256 + col] = f2b(v);
                    } else if (col < 512) {
                        int d = col - 256;
                        kv8[(size_t)row * 512 + (d >> 2) * 8 + (d & 3)] = f2fp8(v);
                    } else {
                        int d = col - 512;
                        kv8[(size_t)row * 512 + (d >> 2) * 8 + 4 + (d & 3)] = f2fp8(v);
                    }
                }
            }
        }
    }
}

// ---------- per-node attention: one wave per dst node ----------
// lane covers dims lane*4..+3 (head=lane>>3). fp8 kv interleaved: one 8B load
// gives {k0..k3, v0..v3}; decode = 4x v_cvt_pk_f32_fp8. 8/4/1 edge phases,
// 2 accumulator chains, explicit scalars only (round-5 LDS-demotion lesson).
__global__ void node_attn(const ushort* __restrict__ qb,
                          const unsigned char* __restrict__ kv8,
                          const int* __restrict__ offsets,
                          const ushort* __restrict__ csr_src,
                          ushort* hbuf,
                          int N) {
    int wid = threadIdx.x >> 6, lane = threadIdx.x & 63;
    int n = blockIdx.x * 4 + wid;
    if (n >= N) return;
    int beg = offsets[n], end = offsets[n + 1];
    ushort4 qu = *(const ushort4*)(qb + (size_t)n * 256 + lane * 4);
    float qx = b2f(qu.x), qy = b2f(qu.y), qz = b2f(qu.z), qw = b2f(qu.w);

    float ax0 = 0.f, ay0 = 0.f, az0 = 0.f, aw0 = 0.f, den0 = 0.f;
    float ax1 = 0.f, ay1 = 0.f, az1 = 0.f, aw1 = 0.f, den1 = 0.f;
    int i = beg;
    #pragma unroll 1
    for (; i + 8 <= end; i += 8) {
        int s0 = csr_src[i], s1 = csr_src[i + 1], s2 = csr_src[i + 2], s3 = csr_src[i + 3];
        int s4 = csr_src[i + 4], s5 = csr_src[i + 5], s6 = csr_src[i + 6], s7 = csr_src[i + 7];
        uint2 u0 = *(const uint2*)(kv8 + (size_t)s0 * 512 + lane * 8);
        uint2 u1 = *(const uint2*)(kv8 + (size_t)s1 * 512 + lane * 8);
        uint2 u2 = *(const uint2*)(kv8 + (size_t)s2 * 512 + lane * 8);
        uint2 u3 = *(const uint2*)(kv8 + (size_t)s3 * 512 + lane * 8);
        uint2 u4 = *(const uint2*)(kv8 + (size_t)s4 * 512 + lane * 8);
        uint2 u5 = *(const uint2*)(kv8 + (size_t)s5 * 512 + lane * 8);
        uint2 u6 = *(const uint2*)(kv8 + (size_t)s6 * 512 + lane * 8);
        uint2 u7 = *(const uint2*)(kv8 + (size_t)s7 * 512 + lane * 8);
        f32x2 ka0 = __builtin_amdgcn_cvt_pk_f32_fp8(u0.x, false), kb0 = __builtin_amdgcn_cvt_pk_f32_fp8(u0.x, true);
        f32x2 ka1 = __builtin_amdgcn_cvt_pk_f32_fp8(u1.x, false), kb1 = __builtin_amdgcn_cvt_pk_f32_fp8(u1.x, true);
        f32x2 ka2 = __builtin_amdgcn_cvt_pk_f32_fp8(u2.x, false), kb2 = __builtin_amdgcn_cvt_pk_f32_fp8(u2.x, true);
        f32x2 ka3 = __builtin_amdgcn_cvt_pk_f32_fp8(u3.x, false), kb3 = __builtin_amdgcn_cvt_pk_f32_fp8(u3.x, true);
        f32x2 ka4 = __builtin_amdgcn_cvt_pk_f32_fp8(u4.x, false), kb4 = __builtin_amdgcn_cvt_pk_f32_fp8(u4.x, true);
        f32x2 ka5 = __builtin_amdgcn_cvt_pk_f32_fp8(u5.x, false), kb5 = __builtin_amdgcn_cvt_pk_f32_fp8(u5.x, true);
        f32x2 ka6 = __builtin_amdgcn_cvt_pk_f32_fp8(u6.x, false), kb6 = __builtin_amdgcn_cvt_pk_f32_fp8(u6.x, true);
        f32x2 ka7 = __builtin_amdgcn_cvt_pk_f32_fp8(u7.x, false), kb7 = __builtin_amdgcn_cvt_pk_f32_fp8(u7.x, true);
        float p0 = qx * ka0.x + qy * ka0.y + qz * kb0.x + qw * kb0.y;
        float p1 = qx * ka1.x + qy * ka1.y + qz * kb1.x + qw * kb1.y;
        float p2 = qx * ka2.x + qy * ka2.y + qz * kb2.x + qw * kb2.y;
        float p3 = qx * ka3.x + qy * ka3.y + qz * kb3.x + qw * kb3.y;
        float p4 = qx * ka4.x + qy * ka4.y + qz * kb4.x + qw * kb4.y;
        float p5 = qx * ka5.x + qy * ka5.y + qz * kb5.x + qw * kb5.y;
        float p6 = qx * ka6.x + qy * ka6.y + qz * kb6.x + qw * kb6.y;
        float p7 = qx * ka7.x + qy * ka7.y + qz * kb7.x + qw * kb7.y;
        p0 += __shfl_xor(p0, 1); p1 += __shfl_xor(p1, 1); p2 += __shfl_xor(p2, 1); p3 += __shfl_xor(p3, 1);
        p4 += __shfl_xor(p4, 1); p5 += __shfl_xor(p5, 1); p6 += __shfl_xor(p6, 1); p7 += __shfl_xor(p7, 1);
        p0 += __shfl_xor(p0, 2); p1 += __shfl_xor(p1, 2); p2 += __shfl_xor(p2, 2); p3 += __shfl_xor(p3, 2);
        p4 += __shfl_xor(p4, 2); p5 += __shfl_xor(p5, 2); p6 += __shfl_xor(p6, 2); p7 += __shfl_xor(p7, 2);
        p0 += __shfl_xor(p0, 4); p1 += __shfl_xor(p1, 4); p2 += __shfl_xor(p2, 4); p3 += __shfl_xor(p3, 4);
        p4 += __shfl_xor(p4, 4); p5 += __shfl_xor(p5, 4); p6 += __shfl_xor(p6, 4); p7 += __shfl_xor(p7, 4);
        float sc0 = exp2f(p0 * EXSCALE), sc1 = exp2f(p1 * EXSCALE);
        float sc2 = exp2f(p2 * EXSCALE), sc3 = exp2f(p3 * EXSCALE);
        float sc4 = exp2f(p4 * EXSCALE), sc5 = exp2f(p5 * EXSCALE);
        float sc6 = exp2f(p6 * EXSCALE), sc7 = exp2f(p7 * EXSCALE);
        den0 += (sc0 + sc2) + (sc4 + sc6);
        den1 += (sc1 + sc3) + (sc5 + sc7);
        f32x2 va0 = __builtin_amdgcn_cvt_pk_f32_fp8(u0.y, false), vb0 = __builtin_amdgcn_cvt_pk_f32_fp8(u0.y, true);
        f32x2 va1 = __builtin_amdgcn_cvt_pk_f32_fp8(u1.y, false), vb1 = __builtin_amdgcn_cvt_pk_f32_fp8(u1.y, true);
        f32x2 va2 = __builtin_amdgcn_cvt_pk_f32_fp8(u2.y, false), vb2 = __builtin_amdgcn_cvt_pk_f32_fp8(u2.y, true);
        f32x2 va3 = __builtin_amdgcn_cvt_pk_f32_fp8(u3.y, false), vb3 = __builtin_amdgcn_cvt_pk_f32_fp8(u3.y, true);
        f32x2 va4 = __builtin_amdgcn_cvt_pk_f32_fp8(u4.y, false), vb4 = __builtin_amdgcn_cvt_pk_f32_fp8(u4.y, true);
        f32x2 va5 = __builtin_amdgcn_cvt_pk_f32_fp8(u5.y, false), vb5 = __builtin_amdgcn_cvt_pk_f32_fp8(u5.y, true);
        f32x2 va6 = __builtin_amdgcn_cvt_pk_f32_fp8(u6.y, false), vb6 = __builtin_amdgcn_cvt_pk_f32_fp8(u6.y, true);
        f32x2 va7 = __builtin_amdgcn_cvt_pk_f32_fp8(u7.y, false), vb7 = __builtin_amdgcn_cvt_pk_f32_fp8(u7.y, true);
        ax0 += sc0 * va0.x + sc2 * va2.x + sc4 * va4.x + sc6 * va6.x;
        ay0 += sc0 * va0.y + sc2 * va2.y + sc4 * va4.y + sc6 * va6.y;
        az0 += sc0 * vb0.x + sc2 * vb2.x + sc4 * vb4.x + sc6 * vb6.x;
        aw0 += sc0 * vb0.y + sc2 * vb2.y + sc4 * vb4.y + sc6 * vb6.y;
        ax1 += sc1 * va1.x + sc3 * va3.x + sc5 * va5.x + sc7 * va7.x;
        ay1 += sc1 * va1.y + sc3 * va3.y + sc5 * va5.y + sc7 * va7.y;
        az1 += sc1 * vb1.x + sc3 * vb3.x + sc5 * vb5.x + sc7 * vb7.x;
        aw1 += sc1 * vb1.y + sc3 * vb3.y + sc5 * vb5.y + sc7 * vb7.y;
    }
    #pragma unroll 1
    for (; i + 4 <= end; i += 4) {
        int s0 = csr_src[i], s1 = csr_src[i + 1], s2 = csr_src[i + 2], s3 = csr_src[i + 3];
        uint2 u0 = *(const uint2*)(kv8 + (size_t)s0 * 512 + lane * 8);
        uint2 u1 = *(const uint2*)(kv8 + (size_t)s1 * 512 + lane * 8);
        uint2 u2 = *(const uint2*)(kv8 + (size_t)s2 * 512 + lane * 8);
        uint2 u3 = *(const uint2*)(kv8 + (size_t)s3 * 512 + lane * 8);
        f32x2 ka0 = __builtin_amdgcn_cvt_pk_f32_fp8(u0.x, false), kb0 = __builtin_amdgcn_cvt_pk_f32_fp8(u0.x, true);
        f32x2 ka1 = __builtin_amdgcn_cvt_pk_f32_fp8(u1.x, false), kb1 = __builtin_amdgcn_cvt_pk_f32_fp8(u1.x, true);
        f32x2 ka2 = __builtin_amdgcn_cvt_pk_f32_fp8(u2.x, false), kb2 = __builtin_amdgcn_cvt_pk_f32_fp8(u2.x, true);
        f32x2 ka3 = __builtin_amdgcn_cvt_pk_f32_fp8(u3.x, false), kb3 = __builtin_amdgcn_cvt_pk_f32_fp8(u3.x, true);
        float p0 = qx * ka0.x + qy * ka0.y + qz * kb0.x + qw * kb0.y;
        float p1 = qx * ka1.x + qy * ka1.y + qz * kb1.x + qw * kb1.y;
        float p2 = qx * ka2.x + qy * ka2.y + qz * kb2.x + qw * kb2.y;
        float p3 = qx * ka3.x + qy * ka3.y + qz * kb3.x + qw * kb3.y;
        p0 += __shfl_xor(p0, 1); p1 += __shfl_xor(p1, 1); p2 += __shfl_xor(p2, 1); p3 += __shfl_xor(p3, 1);
        p0 += __shfl_xor(p0, 2); p1 += __shfl_xor(p1, 2); p2 += __shfl_xor(p2, 2); p3 += __shfl_xor(p3, 2);
        p0 += __shfl_xor(p0, 4); p1 += __shfl_xor(p1, 4); p2 += __shfl_xor(p2, 4); p3 += __shfl_xor(p3, 4);
        float sc0 = exp2f(p0 * EXSCALE), sc1 = exp2f(p1 * EXSCALE);
        float sc2 = exp2f(p2 * EXSCALE), sc3 = exp2f(p3 * EXSCALE);
        den0 += sc0 + sc2;
        den1 += sc1 + sc3;
        f32x2 va0 = __builtin_amdgcn_cvt_pk_f32_fp8(u0.y, false), vb0 = __builtin_amdgcn_cvt_pk_f32_fp8(u0.y, true);
        f32x2 va1 = __builtin_amdgcn_cvt_pk_f32_fp8(u1.y, false), vb1 = __builtin_amdgcn_cvt_pk_f32_fp8(u1.y, true);
        f32x2 va2 = __builtin_amdgcn_cvt_pk_f32_fp8(u2.y, false), vb2 = __builtin_amdgcn_cvt_pk_f32_fp8(u2.y, true);
        f32x2 va3 = __builtin_amdgcn_cvt_pk_f32_fp8(u3.y, false), vb3 = __builtin_amdgcn_cvt_pk_f32_fp8(u3.y, true);
        ax0 += sc0 * va0.x + sc2 * va2.x;
        ay0 += sc0 * va0.y + sc2 * va2.y;
        az0 += sc0 * vb0.x + sc2 * vb2.x;
        aw0 += sc0 * vb0.y + sc2 * vb2.y;
        ax1 += sc1 * va1.x + sc3 * va3.x;
        ay1 += sc1 * va1.y + sc3 * va3.y;
        az1 += sc1 * vb1.x + sc3 * vb3.x;
        aw1 += sc1 * vb1.y + sc3 * vb3.y;
    }
    #pragma unroll 1
    for (; i < end; ++i) {
        int s0 = csr_src[i];
        uint2 u0 = *(const uint2*)(kv8 + (size_t)s0 * 512 + lane * 8);
        f32x2 ka0 = __builtin_amdgcn_cvt_pk_f32_fp8(u0.x, false), kb0 = __builtin_amdgcn_cvt_pk_f32_fp8(u0.x, true);
        float p0 = qx * ka0.x + qy * ka0.y + qz * kb0.x + qw * kb0.y;
        p0 += __shfl_xor(p0, 1);
        p0 += __shfl_xor(p0, 2);
        p0 += __shfl_xor(p0, 4);
        float sc0 = exp2f(p0 * EXSCALE);
        den0 += sc0;
        f32x2 va0 = __builtin_amdgcn_cvt_pk_f32_fp8(u0.y, false), vb0 = __builtin_amdgcn_cvt_pk_f32_fp8(u0.y, true);
        ax0 += sc0 * va0.x; ay0 += sc0 * va0.y;
        az0 += sc0 * vb0.x; aw0 += sc0 * vb0.y;
    }
    float den = den0 + den1;
    float inv = (end > beg) ? (1.0f / den) : 0.f;
    int head = lane >> 3;
    int d0 = (lane & 7) * 4;
    const ushort* hr = hbuf + (size_t)n * 256;
    float r0 = b2f(hr[(d0 + 0) * 8 + head]);
    float r1 = b2f(hr[(d0 + 1) * 8 + head]);
    float r2 = b2f(hr[(d0 + 2) * 8 + head]);
    float r3 = b2f(hr[(d0 + 3) * 8 + head]);
    ushort4 o;
    o.x = f2b((ax0 + ax1) * inv + r0);
    o.y = f2b((ay0 + ay1) * inv + r1);
    o.z = f2b((az0 + az1) * inv + r2);
    o.w = f2b((aw0 + aw1) * inv + r3);
    *(ushort4*)(hbuf + (size_t)n * 256 + lane * 4) = o;
}

extern "C" void kernel_launch(void* const* d_in, const int* in_sizes, int n_in,
                              void* d_out, int out_size, void* d_ws, size_t ws_size,
                              hipStream_t stream) {
    const float* h     = (const float*)d_in[0];
    const int*   src   = (const int*)d_in[1];
    const int*   dst   = (const int*)d_in[2];
    const float* W_qkv = (const float*)d_in[3];
    const float* b_qkv = (const float*)d_in[4];
    const float* W_out = (const float*)d_in[5];
    const float* b_out = (const float*)d_in[6];
    float* out = (float*)d_out;

    int N = in_sizes[0] / 256;
    int E = in_sizes[1];
    int Mpad = (N + 127) & ~127;
    int No   = (N + 16) & ~15;          // padded int stride, int4 alignment

    ushort* qb        = (ushort*)d_ws;                         // Mpad*256 bf16
    unsigned char* kv8 = (unsigned char*)(qb + (size_t)Mpad * 256); // Mpad*512 B fp8
    ushort* Abf       = (ushort*)(kv8 + (size_t)Mpad * 512);   // Mpad*256 bf16 (h, then h2)
    ushort* WTq       = Abf + (size_t)Mpad * 256;              // 768*256
    ushort* WTo       = WTq + 768 * 256;                       // 256*256
    int* counts  = (int*)(WTo + 256 * 256);                    // No
    int* offsets = counts + No;                                // No+1
    int* cursor  = offsets + No;                               // No
    int* bsum    = cursor + No;                                // 32
    int* bbase   = bsum + 32;                                  // 32
    ushort* csr_src = (ushort*)(bbase + 32);                   // E (ushort: N < 65536)

    hipMemsetAsync(counts, 0, (size_t)No * sizeof(int), stream);

    int n4 = N * 64;
    int B0 = (n4 + 255) / 256;
    int B1 = B0 + 1024;
    int BC = (E + 1023) / 1024;
    prep<<<B1 + BC, 256, 0, stream>>>(h, Abf, n4, W_qkv, W_out, WTq, WTo,
                                      dst, counts, E, B0, B1);

    int nb = (N + 4095) / 4096;
    scanA<<<nb, 1024, 0, stream>>>(counts, bsum, N);
    scanB<<<1, 64, 0, stream>>>(bsum, bbase, nb, offsets, N, E);
    scanC<<<nb, 1024, 0, stream>>>(counts, bbase, offsets, cursor, N);
    scatter_edges<<<(E + 255) / 256, 256, 0, stream>>>(src, dst, cursor, csr_src, E);

    int nrb = Mpad / 128;
    gemm_mfma<1><<<nrb * 6, 256, 0, stream>>>(Abf, WTq, b_qkv, nullptr, qb, kv8, N, 6);

    node_attn<<<(N + 3) / 4, 256, 0, stream>>>(qb, kv8, offsets, csr_src, Abf, N);

    gemm_mfma<0><<<nrb * 2, 256, 0, stream>>>(Abf, WTo, b_out, out, nullptr, nullptr, N, 2);
}

// Round 9
// 242.419 us; speedup vs baseline: 1.8569x; 1.0730x over previous
//
#include <hip/hip_runtime.h>
#include <hip/hip_bf16.h>

#define NHEAD 8
#define SCALE 0.17677669529663687f      // 32^-0.5
#define EXSCALE 0.2551149170424794f     // SCALE * log2(e): one mul + v_exp_f32

typedef __attribute__((ext_vector_type(8))) short bf16x8;
typedef __attribute__((ext_vector_type(4))) float f32x4;
typedef __attribute__((ext_vector_type(2))) float f32x2;
typedef __attribute__((ext_vector_type(8))) unsigned short ushort8;

__device__ inline ushort f2b(float f) {          // f32 -> bf16 bits, RNE
    unsigned u = __float_as_uint(f);
    u += 0x7FFFu + ((u >> 16) & 1u);
    return (ushort)(u >> 16);
}
__device__ inline float b2f(ushort b) {          // bf16 bits -> f32 (exact)
    return __uint_as_float(((unsigned)b) << 16);
}

__device__ inline void load_lds16(const ushort* g, ushort* l) {
    __builtin_amdgcn_global_load_lds(
        (const __attribute__((address_space(1))) unsigned*)g,
        (__attribute__((address_space(3))) unsigned*)l, 16, 0, 0);
}

// ---------- fused prep: conv h->bf16 | transpose weights | count dst ----------
__global__ void prep(const float* __restrict__ h, ushort* __restrict__ Abf, int n4,
                     const float* __restrict__ Wq, const float* __restrict__ Wo,
                     ushort* __restrict__ WTq, ushort* __restrict__ WTo,
                     const int* __restrict__ dst, int* __restrict__ counts, int E,
                     int B0, int B1) {
    int bid = blockIdx.x, tid = threadIdx.x;
    if (bid < B0) {
        int i = bid * 256 + tid;
        if (i < n4) {
            float4 v = ((const float4*)h)[i];
            ushort4 o;
            o.x = f2b(v.x); o.y = f2b(v.y); o.z = f2b(v.z); o.w = f2b(v.w);
            ((ushort4*)Abf)[i] = o;
        }
    } else if (bid < B1) {
        int b = bid - B0;
        if (b < 768) {
            WTq[(size_t)b * 256 + tid] = f2b(Wq[(size_t)tid * 768 + b]);
        } else {
            int col = b - 768;
            int c   = ((tid & 31) * 8) + (tid >> 5);   // absorb head-transpose
            WTo[(size_t)col * 256 + tid] = f2b(Wo[(size_t)c * 256 + col]);
        }
    } else {
        int i = (bid - B1) * 1024 + tid * 4;
        if (i + 3 < E) {
            int4 d4 = *(const int4*)(dst + i);
            atomicAdd(&counts[d4.x], 1);
            atomicAdd(&counts[d4.y], 1);
            atomicAdd(&counts[d4.z], 1);
            atomicAdd(&counts[d4.w], 1);
        } else {
            for (int t = 0; t < 4; ++t)
                if (i + t < E) atomicAdd(&counts[dst[i + t]], 1);
        }
    }
}

// ---------- 3-kernel scan ----------
__global__ void scanA(const int* __restrict__ counts, int* __restrict__ bsum, int N) {
    __shared__ int ws[16];
    int tid = threadIdx.x, lane = tid & 63, wid = tid >> 6;
    int i = blockIdx.x * 4096 + tid * 4;
    int s = 0;
    if (i < N) { int4 c = *(const int4*)(counts + i); s = c.x + c.y + c.z + c.w; }
    #pragma unroll
    for (int d = 1; d < 64; d <<= 1) s += __shfl_xor(s, d);
    if (lane == 0) ws[wid] = s;
    __syncthreads();
    if (tid < 16) {
        int v = ws[tid];
        #pragma unroll
        for (int d = 1; d < 16; d <<= 1) v += __shfl_xor(v, d);
        if (tid == 0) bsum[blockIdx.x] = v;
    }
}

__global__ void scanB(const int* __restrict__ bsum, int* __restrict__ bbase, int nb,
                      int* __restrict__ offsets, int N, int E) {
    int t = threadIdx.x;      // 64 threads
    int v = (t < nb) ? bsum[t] : 0;
    int x = v;
    #pragma unroll
    for (int d = 1; d < 64; d <<= 1) {
        int y = __shfl_up(x, d);
        if (t >= d) x += y;
    }
    if (t < nb) bbase[t] = x - v;
    if (t == 0) offsets[N] = E;
}

__global__ void scanC(const int* __restrict__ counts, const int* __restrict__ bbase,
                      int* __restrict__ offsets, int* __restrict__ cursor, int N) {
    __shared__ int wsum[16];
    int tid = threadIdx.x, lane = tid & 63, wid = tid >> 6;
    int i = blockIdx.x * 4096 + tid * 4;
    int4 c = make_int4(0, 0, 0, 0);
    if (i < N) c = *(const int4*)(counts + i);
    int s = c.x + c.y + c.z + c.w;
    int x = s;
    #pragma unroll
    for (int d = 1; d < 64; d <<= 1) {
        int y = __shfl_up(x, d);
        if (lane >= d) x += y;
    }
    if (lane == 63) wsum[wid] = x;
    __syncthreads();
    if (wid == 0 && lane < 16) {
        int w = wsum[lane];
        #pragma unroll
        for (int d = 1; d < 16; d <<= 1) {
            int y = __shfl_up(w, d);
            if (lane >= d) w += y;
        }
        wsum[lane] = w;
    }
    __syncthreads();
    int pre = bbase[blockIdx.x] + (wid ? wsum[wid - 1] : 0) + (x - s);
    if (i < N) {
        int4 o;
        o.x = pre;
        o.y = pre + c.x;
        o.z = o.y + c.y;
        o.w = o.z + c.z;
        *(int4*)(offsets + i) = o;
        *(int4*)(cursor + i) = o;
    }
}

__global__ void scatter_edges(const int* __restrict__ src, const int* __restrict__ dst,
                              int* __restrict__ cursor, ushort* __restrict__ csr_src, int E) {
    int i = blockIdx.x * blockDim.x + threadIdx.x;
    if (i < E) {
        int d = dst[i];
        int pos = atomicAdd(&cursor[d], 1);
        csr_src[pos] = (ushort)src[i];
    }
}

// ---------- MFMA GEMM: C = A[M x 256] * BT[Ncols x 256]^T + bias ----------
// 128x128 tile, BK=32, 4 waves, 16x16x32 bf16 MFMA, global_load_lds width-16.
// 1-D grid + bijective XCD swizzle, cols innermost per XCD (A-tile L2-hot).
// OPERANDS SWAPPED in the MFMA (mfma(B,A)): the C/D transpose puts row=l15,
// cols=(lane>>4)*4+reg -> each lane's f32x4 = 4 CONSECUTIVE cols of one row,
// so the epilogue packs each quad into ONE store (was 64 scalar stores/thread,
// store-issue-bound: 38M stores ~= 62us).
// MODE 0: float4 out. MODE 1: q bf16 ushort4; k/v fp8 packed dword into
// interleaved layout: k dims d..d+3 -> bytes (d>>2)*8, v -> (d>>2)*8+4.
template<int MODE>
__global__ __launch_bounds__(256)
void gemm_mfma(const ushort* __restrict__ A,
               const ushort* __restrict__ BT,
               const float*  __restrict__ bias,
               float* __restrict__ Cf,
               ushort* __restrict__ qb, unsigned char* __restrict__ kv8,
               int M, int NCB) {
    __shared__ ushort As[128 * 32];
    __shared__ ushort Bs[128 * 32];
    const int nwg = gridDim.x;
    const int bid = blockIdx.x;
    const int q8 = nwg >> 3, r8 = nwg & 7, xcd = bid & 7, seq = bid >> 3;
    const int wgid = (xcd < r8 ? xcd * (q8 + 1) : r8 * (q8 + 1) + (xcd - r8) * q8) + seq;
    const int blockRow = (wgid / NCB) * 128;
    const int blockCol = (wgid % NCB) * 128;

    const int tid  = threadIdx.x;
    const int wid  = tid >> 6;
    const int lane = tid & 63;
    const int l15  = lane & 15, l4 = lane >> 4;
    const int wr = wid >> 1, wc = wid & 1;

    f32x4 acc[4][4] = {};

    for (int k0 = 0; k0 < 256; k0 += 32) {
        #pragma unroll
        for (int t = 0; t < 2; ++t) {
            int c   = t * 256 + wid * 64 + lane;   // 16B-chunk index
            int row = c >> 2, ko = (c & 3) * 8;
            load_lds16(A  + (size_t)(blockRow + row) * 256 + k0 + ko,
                       As + (size_t)(t * 256 + wid * 64) * 8);
            load_lds16(BT + (size_t)(blockCol + row) * 256 + k0 + ko,
                       Bs + (size_t)(t * 256 + wid * 64) * 8);
        }
        __syncthreads();
        bf16x8 af[4], bfr[4];
        #pragma unroll
        for (int m = 0; m < 4; ++m)
            af[m] = *(const bf16x8*)&As[(wr * 64 + m * 16 + l15) * 32 + l4 * 8];
        #pragma unroll
        for (int n = 0; n < 4; ++n)
            bfr[n] = *(const bf16x8*)&Bs[(wc * 64 + n * 16 + l15) * 32 + l4 * 8];
        #pragma unroll
        for (int m = 0; m < 4; ++m)
            #pragma unroll
            for (int n = 0; n < 4; ++n)
                acc[m][n] = __builtin_amdgcn_mfma_f32_16x16x32_bf16(bfr[n], af[m], acc[m][n], 0, 0, 0);
        __syncthreads();
    }

    #pragma unroll
    for (int m = 0; m < 4; ++m) {
        int row = blockRow + wr * 64 + m * 16 + l15;    // lane-local output row
        if (row >= M) continue;
        #pragma unroll
        for (int n = 0; n < 4; ++n) {
            int colb = blockCol + wc * 64 + n * 16 + l4 * 4;   // 4 consecutive cols
            float4 b4 = *(const float4*)(bias + colb);
            float v0 = acc[m][n][0] + b4.x;
            float v1 = acc[m][n][1] + b4.y;
            float v2 = acc[m][n][2] + b4.z;
            float v3 = acc[m][n][3] + b4.w;
            if (MODE == 0) {
                *(float4*)(Cf + (size_t)row * 256 + colb) = make_float4(v0, v1, v2, v3);
            } else {
                if (colb < 256) {
                    ushort4 o;
                    o.x = f2b(v0); o.y = f2b(v1); o.z = f2b(v2); o.w = f2b(v3);
                    *(ushort4*)(qb + (size_t)row * 256 + colb) = o;
                } else if (colb < 512) {
                    int d = colb - 256;
                    unsigned u = __builtin_amdgcn_cvt_pk_fp8_f32(v0, v1, 0u, false);
                    u = __builtin_amdgcn_cvt_pk_fp8_f32(v2, v3, u, true);
                    *(unsigned*)(kv8 + (size_t)row * 512 + (d >> 2) * 8) = u;
                } else {
                    int d = colb - 512;
                    unsigned u = __builtin_amdgcn_cvt_pk_fp8_f32(v0, v1, 0u, false);
                    u = __builtin_amdgcn_cvt_pk_fp8_f32(v2, v3, u, true);
                    *(unsigned*)(kv8 + (size_t)row * 512 + (d >> 2) * 8 + 4) = u;
                }
            }
        }
    }
}

// ---------- per-node attention: one wave per dst node ----------
// lane covers dims lane*4..+3 (head=lane>>3). fp8 kv interleaved: one 8B load
// gives {k0..k3, v0..v3}; decode = 4x v_cvt_pk_f32_fp8. 8/4/1 edge phases,
// 2 accumulator chains, explicit scalars only (round-5 LDS-demotion lesson).
__global__ void node_attn(const ushort* __restrict__ qb,
                          const unsigned char* __restrict__ kv8,
                          const int* __restrict__ offsets,
                          const ushort* __restrict__ csr_src,
                          ushort* hbuf,
                          int N) {
    int wid = threadIdx.x >> 6, lane = threadIdx.x & 63;
    int n = blockIdx.x * 4 + wid;
    if (n >= N) return;
    int beg = offsets[n], end = offsets[n + 1];
    ushort4 qu = *(const ushort4*)(qb + (size_t)n * 256 + lane * 4);
    float qx = b2f(qu.x), qy = b2f(qu.y), qz = b2f(qu.z), qw = b2f(qu.w);

    float ax0 = 0.f, ay0 = 0.f, az0 = 0.f, aw0 = 0.f, den0 = 0.f;
    float ax1 = 0.f, ay1 = 0.f, az1 = 0.f, aw1 = 0.f, den1 = 0.f;
    int i = beg;
    #pragma unroll 1
    for (; i + 8 <= end; i += 8) {
        int s0 = csr_src[i], s1 = csr_src[i + 1], s2 = csr_src[i + 2], s3 = csr_src[i + 3];
        int s4 = csr_src[i + 4], s5 = csr_src[i + 5], s6 = csr_src[i + 6], s7 = csr_src[i + 7];
        uint2 u0 = *(const uint2*)(kv8 + (size_t)s0 * 512 + lane * 8);
        uint2 u1 = *(const uint2*)(kv8 + (size_t)s1 * 512 + lane * 8);
        uint2 u2 = *(const uint2*)(kv8 + (size_t)s2 * 512 + lane * 8);
        uint2 u3 = *(const uint2*)(kv8 + (size_t)s3 * 512 + lane * 8);
        uint2 u4 = *(const uint2*)(kv8 + (size_t)s4 * 512 + lane * 8);
        uint2 u5 = *(const uint2*)(kv8 + (size_t)s5 * 512 + lane * 8);
        uint2 u6 = *(const uint2*)(kv8 + (size_t)s6 * 512 + lane * 8);
        uint2 u7 = *(const uint2*)(kv8 + (size_t)s7 * 512 + lane * 8);
        f32x2 ka0 = __builtin_amdgcn_cvt_pk_f32_fp8(u0.x, false), kb0 = __builtin_amdgcn_cvt_pk_f32_fp8(u0.x, true);
        f32x2 ka1 = __builtin_amdgcn_cvt_pk_f32_fp8(u1.x, false), kb1 = __builtin_amdgcn_cvt_pk_f32_fp8(u1.x, true);
        f32x2 ka2 = __builtin_amdgcn_cvt_pk_f32_fp8(u2.x, false), kb2 = __builtin_amdgcn_cvt_pk_f32_fp8(u2.x, true);
        f32x2 ka3 = __builtin_amdgcn_cvt_pk_f32_fp8(u3.x, false), kb3 = __builtin_amdgcn_cvt_pk_f32_fp8(u3.x, true);
        f32x2 ka4 = __builtin_amdgcn_cvt_pk_f32_fp8(u4.x, false), kb4 = __builtin_amdgcn_cvt_pk_f32_fp8(u4.x, true);
        f32x2 ka5 = __builtin_amdgcn_cvt_pk_f32_fp8(u5.x, false), kb5 = __builtin_amdgcn_cvt_pk_f32_fp8(u5.x, true);
        f32x2 ka6 = __builtin_amdgcn_cvt_pk_f32_fp8(u6.x, false), kb6 = __builtin_amdgcn_cvt_pk_f32_fp8(u6.x, true);
        f32x2 ka7 = __builtin_amdgcn_cvt_pk_f32_fp8(u7.x, false), kb7 = __builtin_amdgcn_cvt_pk_f32_fp8(u7.x, true);
        float p0 = qx * ka0.x + qy * ka0.y + qz * kb0.x + qw * kb0.y;
        float p1 = qx * ka1.x + qy * ka1.y + qz * kb1.x + qw * kb1.y;
        float p2 = qx * ka2.x + qy * ka2.y + qz * kb2.x + qw * kb2.y;
        float p3 = qx * ka3.x + qy * ka3.y + qz * kb3.x + qw * kb3.y;
        float p4 = qx * ka4.x + qy * ka4.y + qz * kb4.x + qw * kb4.y;
        float p5 = qx * ka5.x + qy * ka5.y + qz * kb5.x + qw * kb5.y;
        float p6 = qx * ka6.x + qy * ka6.y + qz * kb6.x + qw * kb6.y;
        float p7 = qx * ka7.x + qy * ka7.y + qz * kb7.x + qw * kb7.y;
        p0 += __shfl_xor(p0, 1); p1 += __shfl_xor(p1, 1); p2 += __shfl_xor(p2, 1); p3 += __shfl_xor(p3, 1);
        p4 += __shfl_xor(p4, 1); p5 += __shfl_xor(p5, 1); p6 += __shfl_xor(p6, 1); p7 += __shfl_xor(p7, 1);
        p0 += __shfl_xor(p0, 2); p1 += __shfl_xor(p1, 2); p2 += __shfl_xor(p2, 2); p3 += __shfl_xor(p3, 2);
        p4 += __shfl_xor(p4, 2); p5 += __shfl_xor(p5, 2); p6 += __shfl_xor(p6, 2); p7 += __shfl_xor(p7, 2);
        p0 += __shfl_xor(p0, 4); p1 += __shfl_xor(p1, 4); p2 += __shfl_xor(p2, 4); p3 += __shfl_xor(p3, 4);
        p4 += __shfl_xor(p4, 4); p5 += __shfl_xor(p5, 4); p6 += __shfl_xor(p6, 4); p7 += __shfl_xor(p7, 4);
        float sc0 = exp2f(p0 * EXSCALE), sc1 = exp2f(p1 * EXSCALE);
        float sc2 = exp2f(p2 * EXSCALE), sc3 = exp2f(p3 * EXSCALE);
        float sc4 = exp2f(p4 * EXSCALE), sc5 = exp2f(p5 * EXSCALE);
        float sc6 = exp2f(p6 * EXSCALE), sc7 = exp2f(p7 * EXSCALE);
        den0 += (sc0 + sc2) + (sc4 + sc6);
        den1 += (sc1 + sc3) + (sc5 + sc7);
        f32x2 va0 = __builtin_amdgcn_cvt_pk_f32_fp8(u0.y, false), vb0 = __builtin_amdgcn_cvt_pk_f32_fp8(u0.y, true);
        f32x2 va1 = __builtin_amdgcn_cvt_pk_f32_fp8(u1.y, false), vb1 = __builtin_amdgcn_cvt_pk_f32_fp8(u1.y, true);
        f32x2 va2 = __builtin_amdgcn_cvt_pk_f32_fp8(u2.y, false), vb2 = __builtin_amdgcn_cvt_pk_f32_fp8(u2.y, true);
        f32x2 va3 = __builtin_amdgcn_cvt_pk_f32_fp8(u3.y, false), vb3 = __builtin_amdgcn_cvt_pk_f32_fp8(u3.y, true);
        f32x2 va4 = __builtin_amdgcn_cvt_pk_f32_fp8(u4.y, false), vb4 = __builtin_amdgcn_cvt_pk_f32_fp8(u4.y, true);
        f32x2 va5 = __builtin_amdgcn_cvt_pk_f32_fp8(u5.y, false), vb5 = __builtin_amdgcn_cvt_pk_f32_fp8(u5.y, true);
        f32x2 va6 = __builtin_amdgcn_cvt_pk_f32_fp8(u6.y, false), vb6 = __builtin_amdgcn_cvt_pk_f32_fp8(u6.y, true);
        f32x2 va7 = __builtin_amdgcn_cvt_pk_f32_fp8(u7.y, false), vb7 = __builtin_amdgcn_cvt_pk_f32_fp8(u7.y, true);
        ax0 += sc0 * va0.x + sc2 * va2.x + sc4 * va4.x + sc6 * va6.x;
        ay0 += sc0 * va0.y + sc2 * va2.y + sc4 * va4.y + sc6 * va6.y;
        az0 += sc0 * vb0.x + sc2 * vb2.x + sc4 * vb4.x + sc6 * vb6.x;
        aw0 += sc0 * vb0.y + sc2 * vb2.y + sc4 * vb4.y + sc6 * vb6.y;
        ax1 += sc1 * va1.x + sc3 * va3.x + sc5 * va5.x + sc7 * va7.x;
        ay1 += sc1 * va1.y + sc3 * va3.y + sc5 * va5.y + sc7 * va7.y;
        az1 += sc1 * vb1.x + sc3 * vb3.x + sc5 * vb5.x + sc7 * vb7.x;
        aw1 += sc1 * vb1.y + sc3 * vb3.y + sc5 * vb5.y + sc7 * vb7.y;
    }
    #pragma unroll 1
    for (; i + 4 <= end; i += 4) {
        int s0 = csr_src[i], s1 = csr_src[i + 1], s2 = csr_src[i + 2], s3 = csr_src[i + 3];
        uint2 u0 = *(const uint2*)(kv8 + (size_t)s0 * 512 + lane * 8);
        uint2 u1 = *(const uint2*)(kv8 + (size_t)s1 * 512 + lane * 8);
        uint2 u2 = *(const uint2*)(kv8 + (size_t)s2 * 512 + lane * 8);
        uint2 u3 = *(const uint2*)(kv8 + (size_t)s3 * 512 + lane * 8);
        f32x2 ka0 = __builtin_amdgcn_cvt_pk_f32_fp8(u0.x, false), kb0 = __builtin_amdgcn_cvt_pk_f32_fp8(u0.x, true);
        f32x2 ka1 = __builtin_amdgcn_cvt_pk_f32_fp8(u1.x, false), kb1 = __builtin_amdgcn_cvt_pk_f32_fp8(u1.x, true);
        f32x2 ka2 = __builtin_amdgcn_cvt_pk_f32_fp8(u2.x, false), kb2 = __builtin_amdgcn_cvt_pk_f32_fp8(u2.x, true);
        f32x2 ka3 = __builtin_amdgcn_cvt_pk_f32_fp8(u3.x, false), kb3 = __builtin_amdgcn_cvt_pk_f32_fp8(u3.x, true);
        float p0 = qx * ka0.x + qy * ka0.y + qz * kb0.x + qw * kb0.y;
        float p1 = qx * ka1.x + qy * ka1.y + qz * kb1.x + qw * kb1.y;
        float p2 = qx * ka2.x + qy * ka2.y + qz * kb2.x + qw * kb2.y;
        float p3 = qx * ka3.x + qy * ka3.y + qz * kb3.x + qw * kb3.y;
        p0 += __shfl_xor(p0, 1); p1 += __shfl_xor(p1, 1); p2 += __shfl_xor(p2, 1); p3 += __shfl_xor(p3, 1);
        p0 += __shfl_xor(p0, 2); p1 += __shfl_xor(p1, 2); p2 += __shfl_xor(p2, 2); p3 += __shfl_xor(p3, 2);
        p0 += __shfl_xor(p0, 4); p1 += __shfl_xor(p1, 4); p2 += __shfl_xor(p2, 4); p3 += __shfl_xor(p3, 4);
        float sc0 = exp2f(p0 * EXSCALE), sc1 = exp2f(p1 * EXSCALE);
        float sc2 = exp2f(p2 * EXSCALE), sc3 = exp2f(p3 * EXSCALE);
        den0 += sc0 + sc2;
        den1 += sc1 + sc3;
        f32x2 va0 = __builtin_amdgcn_cvt_pk_f32_fp8(u0.y, false), vb0 = __builtin_amdgcn_cvt_pk_f32_fp8(u0.y, true);
        f32x2 va1 = __builtin_amdgcn_cvt_pk_f32_fp8(u1.y, false), vb1 = __builtin_amdgcn_cvt_pk_f32_fp8(u1.y, true);
        f32x2 va2 = __builtin_amdgcn_cvt_pk_f32_fp8(u2.y, false), vb2 = __builtin_amdgcn_cvt_pk_f32_fp8(u2.y, true);
        f32x2 va3 = __builtin_amdgcn_cvt_pk_f32_fp8(u3.y, false), vb3 = __builtin_amdgcn_cvt_pk_f32_fp8(u3.y, true);
        ax0 += sc0 * va0.x + sc2 * va2.x;
        ay0 += sc0 * va0.y + sc2 * va2.y;
        az0 += sc0 * vb0.x + sc2 * vb2.x;
        aw0 += sc0 * vb0.y + sc2 * vb2.y;
        ax1 += sc1 * va1.x + sc3 * va3.x;
        ay1 += sc1 * va1.y + sc3 * va3.y;
        az1 += sc1 * vb1.x + sc3 * vb3.x;
        aw1 += sc1 * vb1.y + sc3 * vb3.y;
    }
    #pragma unroll 1
    for (; i < end; ++i) {
        int s0 = csr_src[i];
        uint2 u0 = *(const uint2*)(kv8 + (size_t)s0 * 512 + lane * 8);
        f32x2 ka0 = __builtin_amdgcn_cvt_pk_f32_fp8(u0.x, false), kb0 = __builtin_amdgcn_cvt_pk_f32_fp8(u0.x, true);
        float p0 = qx * ka0.x + qy * ka0.y + qz * kb0.x + qw * kb0.y;
        p0 += __shfl_xor(p0, 1);
        p0 += __shfl_xor(p0, 2);
        p0 += __shfl_xor(p0, 4);
        float sc0 = exp2f(p0 * EXSCALE);
        den0 += sc0;
        f32x2 va0 = __builtin_amdgcn_cvt_pk_f32_fp8(u0.y, false), vb0 = __builtin_amdgcn_cvt_pk_f32_fp8(u0.y, true);
        ax0 += sc0 * va0.x; ay0 += sc0 * va0.y;
        az0 += sc0 * vb0.x; aw0 += sc0 * vb0.y;
    }
    float den = den0 + den1;
    float inv = (end > beg) ? (1.0f / den) : 0.f;
    int head = lane >> 3;
    int d0 = (lane & 7) * 4;
    const ushort* hr = hbuf + (size_t)n * 256;
    float r0 = b2f(hr[(d0 + 0) * 8 + head]);
    float r1 = b2f(hr[(d0 + 1) * 8 + head]);
    float r2 = b2f(hr[(d0 + 2) * 8 + head]);
    float r3 = b2f(hr[(d0 + 3) * 8 + head]);
    ushort4 o;
    o.x = f2b((ax0 + ax1) * inv + r0);
    o.y = f2b((ay0 + ay1) * inv + r1);
    o.z = f2b((az0 + az1) * inv + r2);
    o.w = f2b((aw0 + aw1) * inv + r3);
    *(ushort4*)(hbuf + (size_t)n * 256 + lane * 4) = o;
}

extern "C" void kernel_launch(void* const* d_in, const int* in_sizes, int n_in,
                              void* d_out, int out_size, void* d_ws, size_t ws_size,
                              hipStream_t stream) {
    const float* h     = (const float*)d_in[0];
    const int*   src   = (const int*)d_in[1];
    const int*   dst   = (const int*)d_in[2];
    const float* W_qkv = (const float*)d_in[3];
    const float* b_qkv = (const float*)d_in[4];
    const float* W_out = (const float*)d_in[5];
    const float* b_out = (const float*)d_in[6];
    float* out = (float*)d_out;

    int N = in_sizes[0] / 256;
    int E = in_sizes[1];
    int Mpad = (N + 127) & ~127;
    int No   = (N + 16) & ~15;          // padded int stride, int4 alignment

    ushort* qb        = (ushort*)d_ws;                         // Mpad*256 bf16
    unsigned char* kv8 = (unsigned char*)(qb + (size_t)Mpad * 256); // Mpad*512 B fp8
    ushort* Abf       = (ushort*)(kv8 + (size_t)Mpad * 512);   // Mpad*256 bf16 (h, then h2)
    ushort* WTq       = Abf + (size_t)Mpad * 256;              // 768*256
    ushort* WTo       = WTq + 768 * 256;                       // 256*256
    int* counts  = (int*)(WTo + 256 * 256);                    // No
    int* offsets = counts + No;                                // No+1
    int* cursor  = offsets + No;                               // No
    int* bsum    = cursor + No;                                // 32
    int* bbase   = bsum + 32;                                  // 32
    ushort* csr_src = (ushort*)(bbase + 32);                   // E (ushort: N < 65536)

    hipMemsetAsync(counts, 0, (size_t)No * sizeof(int), stream);

    int n4 = N * 64;
    int B0 = (n4 + 255) / 256;
    int B1 = B0 + 1024;
    int BC = (E + 1023) / 1024;
    prep<<<B1 + BC, 256, 0, stream>>>(h, Abf, n4, W_qkv, W_out, WTq, WTo,
                                      dst, counts, E, B0, B1);

    int nb = (N + 4095) / 4096;
    scanA<<<nb, 1024, 0, stream>>>(counts, bsum, N);
    scanB<<<1, 64, 0, stream>>>(bsum, bbase, nb, offsets, N, E);
    scanC<<<nb, 1024, 0, stream>>>(counts, bbase, offsets, cursor, N);
    scatter_edges<<<(E + 255) / 256, 256, 0, stream>>>(src, dst, cursor, csr_src, E);

    int nrb = Mpad / 128;
    gemm_mfma<1><<<nrb * 6, 256, 0, stream>>>(Abf, WTq, b_qkv, nullptr, qb, kv8, N, 6);

    node_attn<<<(N + 3) / 4, 256, 0, stream>>>(qb, kv8, offsets, csr_src, Abf, N);

    gemm_mfma<0><<<nrb * 2, 256, 0, stream>>>(Abf, WTo, b_out, out, nullptr, nullptr, N, 2);
}